// Round 3
// baseline (225.621 us; speedup 1.0000x reference)
//
#include <hip/hip_runtime.h>
#include <hip/hip_bf16.h>

#define BATCH 32
#define DZ    8192
#define LG    576
#define LL    256
#define CH    512

// ---- ws layout (byte offsets); ws_size = 256 MiB (poison fill = 262144 KB) ----
#define OFF_S      0                          // float[2*1024] raw Gram S
#define OFF_BSUM   8192                       // double[32*5]
#define OFF_SELSUM 9472                       // double[4*32]
#define OFF_CNT    10496                      // u32 featDone, u32 selDone
#define OFF_NG     10560                      // float[BATCH*LG]
#define OFF_NL     84288                      // float[BATCH*LL]
#define OFF_RNN    117056                     // u64[BATCH*LG]
#define OFF_CNN    264512                     // u64[BATCH*LL]  (contiguous with RNN)
#define OFF_ABF    330048                     // bf16 bits [BATCH*LG*CH]
#define OFF_BBF    19204416                   // bf16 bits [BATCH*LL*CH]
#define WS_NEED    27593024

typedef __attribute__((ext_vector_type(8))) short bf16x8;
typedef __attribute__((ext_vector_type(4))) float f32x4;

__device__ __forceinline__ unsigned short f2bf(float x) {
  union { __hip_bfloat16 h; unsigned short u; } cv;
  cv.h = __float2bfloat16(x);
  return cv.u;
}

// -------- selection (unchanged math) --------
struct SelSmem {
  unsigned long long keys[LG];
  unsigned int nnm[LG];
  float cxy[2 * LG];
  unsigned int plist[40];
  unsigned int cnt;
  float fred[4];
};

template <int V>
__device__ __forceinline__ void sel_case(
    SelSmem& sm, int b,
    const float* __restrict__ zgf, const float* __restrict__ zlf,
    const float* __restrict__ gg, const float* __restrict__ gl,
    const unsigned long long* __restrict__ rowNN,
    const unsigned long long* __restrict__ colNN,
    double* __restrict__ selsum) {
  constexpr bool GDIR = (V == 0 || V == 2);
  constexpr int L1 = GDIR ? LG : LL;
  constexpr int L2 = GDIR ? LL : LG;
  constexpr int M  = GDIR ? 20 : 4;
  constexpr int NR = (L1 + 255) / 256;
  const float* fin  = GDIR ? zgf + (size_t)b * LG * CH : zlf + (size_t)b * LL * CH;
  const float* fcan = GDIR ? zlf + (size_t)b * LL * CH : zgf + (size_t)b * LG * CH;
  int tid = threadIdx.x, lane = tid & 63, wv = tid >> 6;
  if (tid == 0) sm.cnt = 0;

  if constexpr (V < 2) {
    const unsigned long long* src =
        (V == 0) ? rowNN + (size_t)b * LG : colNN + (size_t)b * LL;
    #pragma unroll
    for (int s = 0; s < NR; ++s) {
      int l = tid + s * 256;
      if (l < L1) {
        unsigned long long p = src[l];
        sm.keys[l] = (p & 0xFFFFFFFF00000000ull) | (unsigned)l;
        sm.nnm[l] = (unsigned)(p & 0xFFFFFFFFu);
      }
    }
  } else {
    const float* gin  = (V == 2) ? gg + (size_t)b * LG * 2 : gl + (size_t)b * LL * 2;
    const float* gcan = (V == 2) ? gl + (size_t)b * LL * 2 : gg + (size_t)b * LG * 2;
    #pragma unroll
    for (int s = 0; s < (2 * L2 + 255) / 256; ++s) {
      int i = tid + s * 256;
      if (i < 2 * L2) sm.cxy[i] = gcan[i];
    }
    __syncthreads();
    float x[NR], y[NR], bd[NR];
    unsigned bi[NR];
    #pragma unroll
    for (int s = 0; s < NR; ++s) {
      int l = tid + s * 256;
      x[s] = (l < L1) ? gin[2 * l] : 0.f;
      y[s] = (l < L1) ? gin[2 * l + 1] : 0.f;
      bd[s] = 3.4e38f; bi[s] = 0;
    }
    const float2* c2 = (const float2*)sm.cxy;
    for (int m2 = 0; m2 < L2; m2 += 8) {
      float2 cc[8];
      #pragma unroll
      for (int u = 0; u < 8; ++u) cc[u] = c2[m2 + u];
      #pragma unroll
      for (int u = 0; u < 8; ++u)
        #pragma unroll
        for (int s = 0; s < NR; ++s) {
          float dx = x[s] - cc[u].x, dy = y[s] - cc[u].y;
          float d2 = dx * dx + dy * dy;
          if (d2 < bd[s]) { bd[s] = d2; bi[s] = (unsigned)(m2 + u); }  // first-min
        }
    }
    #pragma unroll
    for (int s = 0; s < NR; ++s) {
      int l = tid + s * 256;
      if (l < L1) {
        sm.keys[l] = ((unsigned long long)__float_as_uint(bd[s]) << 32) | (unsigned)l;
        sm.nnm[l] = bi[s];
      }
    }
  }
  __syncthreads();

  unsigned long long myk[NR];
  int rk[NR];
  #pragma unroll
  for (int s = 0; s < NR; ++s) {
    int l = tid + s * 256;
    myk[s] = (l < L1) ? sm.keys[l] : ~0ull;
    rk[s] = 0;
  }
  for (int j = 0; j < L1; j += 8) {
    unsigned long long kk[8];
    #pragma unroll
    for (int u = 0; u < 8; ++u) kk[u] = sm.keys[j + u];
    #pragma unroll
    for (int u = 0; u < 8; ++u)
      #pragma unroll
      for (int s = 0; s < NR; ++s) rk[s] += (kk[u] < myk[s]) ? 1 : 0;
  }
  #pragma unroll
  for (int s = 0; s < NR; ++s) {
    int l = tid + s * 256;
    if (l < L1 && rk[s] < M) {
      unsigned slot = atomicAdd(&sm.cnt, 1u);
      sm.plist[2 * slot] = (unsigned)l;
      sm.plist[2 * slot + 1] = sm.nnm[l];
    }
  }
  __syncthreads();

  float part = 0.f;
  #pragma unroll
  for (int rr = 0; rr < M / 4; ++rr) {
    int r = wv + rr * 4;
    const float4* a4 = (const float4*)(fin + (size_t)sm.plist[2 * r] * CH);
    const float4* c4 = (const float4*)(fcan + (size_t)sm.plist[2 * r + 1] * CH);
    float4 xa = a4[lane * 2], xb = a4[lane * 2 + 1];
    float4 ya = c4[lane * 2], yb = c4[lane * 2 + 1];
    float d0 = xa.x - ya.x, d1 = xa.y - ya.y, d2 = xa.z - ya.z, d3 = xa.w - ya.w;
    float d4 = xb.x - yb.x, d5 = xb.y - yb.y, d6 = xb.z - yb.z, d7 = xb.w - yb.w;
    part += d0 * d0 + d1 * d1 + d2 * d2 + d3 * d3 +
            d4 * d4 + d5 * d5 + d6 * d6 + d7 * d7;
  }
  for (int s = 32; s; s >>= 1) part += __shfl_down(part, s);
  if (lane == 0) sm.fred[wv] = part;
  __syncthreads();
  if (tid == 0)
    selsum[V * 32 + b] = (double)(sm.fred[0] + sm.fred[1] + sm.fred[2] + sm.fred[3]);
}

// ==================== launch 1: prep + stats + gram + sel V2/V3 ====================
// blk [0,6656)     : prep (fp32->bf16 ws, norms, NN init; blk0 zeroes counters)
// blk [6656,6688)  : per-feature stats
// blk [6688,7744)  : raw Gram entries
// blk [7744,7808)  : grid-space sel V2/V3
#define NPREP 6656
__global__ __launch_bounds__(256) void k_front2(
    const float* __restrict__ za, const float* __restrict__ zb,
    const float* __restrict__ zgf, const float* __restrict__ zlf,
    const float* __restrict__ gg, const float* __restrict__ gl,
    double* __restrict__ bsum, float* __restrict__ S,
    unsigned short* __restrict__ Abf, unsigned short* __restrict__ Bbf,
    float* __restrict__ ng, float* __restrict__ nl,
    unsigned long long* __restrict__ nnInit,
    unsigned int* __restrict__ cnt,
    double* __restrict__ selsum) {
  __shared__ __align__(16) char smem[12032];
  int tid = threadIdx.x, lane = tid & 63, wv = tid >> 6;
  int blk = blockIdx.x;

  if (blk < NPREP) {
    if (blk == 0 && tid == 0) {
      __hip_atomic_store(&cnt[0], 0u, __ATOMIC_RELAXED, __HIP_MEMORY_SCOPE_AGENT);
      __hip_atomic_store(&cnt[1], 0u, __ATOMIC_RELAXED, __HIP_MEMORY_SCOPE_AGENT);
    }
    int row = blk * 4 + wv;
    if (lane == 0) nnInit[row] = ~0ull;       // rowNN/colNN contiguous, 1:1 rows
    const float* src; unsigned short* dst; float* nrm;
    if (row < BATCH * LG) {
      src = zgf + (size_t)row * CH; dst = Abf + (size_t)row * CH; nrm = ng + row;
    } else {
      int rr = row - BATCH * LG;
      src = zlf + (size_t)rr * CH; dst = Bbf + (size_t)rr * CH; nrm = nl + rr;
    }
    const float4* s4 = (const float4*)src;
    float4 v0 = s4[lane * 2], v1 = s4[lane * 2 + 1];
    float ss = v0.x * v0.x + v0.y * v0.y + v0.z * v0.z + v0.w * v0.w +
               v1.x * v1.x + v1.y * v1.y + v1.z * v1.z + v1.w * v1.w;
    union { unsigned short h[8]; uint4 u; } pk;
    pk.h[0] = f2bf(v0.x); pk.h[1] = f2bf(v0.y); pk.h[2] = f2bf(v0.z); pk.h[3] = f2bf(v0.w);
    pk.h[4] = f2bf(v1.x); pk.h[5] = f2bf(v1.y); pk.h[6] = f2bf(v1.z); pk.h[7] = f2bf(v1.w);
    *(uint4*)(dst + lane * 8) = pk.u;
    for (int off = 32; off; off >>= 1) ss += __shfl_down(ss, off);
    if (lane == 0) *nrm = ss;
    return;
  }

  if (blk < NPREP + 32) {
    float (*sred)[5] = (float(*)[5])smem;
    int blkS = blk - NPREP;
    int i = blkS * 256 + tid;
    float sa = 0.f, qa = 0.f, sb = 0.f, qb = 0.f, si = 0.f;
    #pragma unroll 8
    for (int b = 0; b < BATCH; ++b) {
      float va = za[(size_t)b * DZ + i];
      float vb = zb[(size_t)b * DZ + i];
      sa += va; qa += va * va;
      sb += vb; qb += vb * vb;
      float d = va - vb; si += d * d;
    }
    float ssa = qa - sa * sa * (1.f / 32.f);
    float ssb = qb - sb * sb * (1.f / 32.f);
    float v0 = si;
    float v1 = fmaxf(0.f, 1.f - sqrtf(ssa * (1.f / 31.f) + 1e-4f));
    float v2 = fmaxf(0.f, 1.f - sqrtf(ssb * (1.f / 31.f) + 1e-4f));
    float v3 = ssa * ssa, v4 = ssb * ssb;
    for (int off = 32; off; off >>= 1) {
      v0 += __shfl_down(v0, off); v1 += __shfl_down(v1, off);
      v2 += __shfl_down(v2, off); v3 += __shfl_down(v3, off);
      v4 += __shfl_down(v4, off);
    }
    if (lane == 0) {
      sred[wv][0] = v0; sred[wv][1] = v1; sred[wv][2] = v2;
      sred[wv][3] = v3; sred[wv][4] = v4;
    }
    __syncthreads();
    if (tid < 5)
      bsum[blkS * 5 + tid] =
          (double)(sred[0][tid] + sred[1][tid] + sred[2][tid] + sred[3][tid]);
    return;
  }

  if (blk < NPREP + 32 + 1056) {
    float (*sred)[5] = (float(*)[5])smem;
    int e = blk - (NPREP + 32);               // 0..1055
    int zi = e >= 528; if (zi) e -= 528;
    const float* z = zi ? zb : za;
    float* Sz = S + zi * 1024;
    int p = 0, rem = e;
    while (rem >= 32 - p) { rem -= 32 - p; ++p; }
    int q = p + rem;
    const float4* zp = (const float4*)(z + (size_t)p * DZ);
    const float4* zq = (const float4*)(z + (size_t)q * DZ);
    float s = 0.f;
    #pragma unroll
    for (int ii = 0; ii < 8; ++ii) {
      int i = tid + ii * 256;
      float4 a = zp[i], bb = zq[i];
      s += a.x * bb.x + a.y * bb.y + a.z * bb.z + a.w * bb.w;
    }
    for (int off = 32; off; off >>= 1) s += __shfl_down(s, off);
    if (lane == 0) sred[wv][0] = s;
    __syncthreads();
    if (tid == 0) {
      float r = sred[0][0] + sred[1][0] + sred[2][0] + sred[3][0];
      Sz[p * 32 + q] = r;
      if (p != q) Sz[q * 32 + p] = r;
    }
    return;
  }

  // ---- grid-space sel V2/V3 (independent of feat NN) ----
  {
    SelSmem& sm = *reinterpret_cast<SelSmem*>(smem);
    int e = blk - (NPREP + 32 + 1056);
    int b2 = e >> 1;
    if (e & 1) sel_case<3>(sm, b2, zgf, zlf, gg, gl, (const unsigned long long*)0,
                           (const unsigned long long*)0, selsum);
    else       sel_case<2>(sm, b2, zgf, zlf, gg, gl, (const unsigned long long*)0,
                           (const unsigned long long*)0, selsum);
  }
}

// ==================== launch 2: feat MFMA + (gated) sel V0/V1 + final ====================
// blk [0,576)   : feat tiles; after NN atomicMin -> release-add featDone
// blk [576,640) : spin on featDone==576 -> sel V0/V1 -> selDone; last does final
// Co-residency: LDS 27.9KB -> 5 blocks/CU -> 1280 slots >= 640 blocks (no deadlock).
struct TailSmem {
  SelSmem sel;
  float t[2][32];
  double sacc[5];
  double smf[4];
  int isLast;
};

__global__ __launch_bounds__(256) void k_back(
    const float* __restrict__ zgf, const float* __restrict__ zlf,
    const float* __restrict__ gg, const float* __restrict__ gl,
    const unsigned short* __restrict__ Abf, const unsigned short* __restrict__ Bbf,
    const float* __restrict__ ng, const float* __restrict__ nl,
    unsigned long long* __restrict__ rowNN, unsigned long long* __restrict__ colNN,
    double* __restrict__ selsum, const double* __restrict__ bsum,
    const float* __restrict__ S, unsigned int* __restrict__ cnt,
    float* __restrict__ out) {
  __shared__ __align__(16) char smem[27904];
  int tid = threadIdx.x, lane = tid & 63, wv = tid >> 6;
  int blk = blockIdx.x;

  if (blk < 576) {
    // XCD swizzle (576 % 8 == 0)
    int fs = (blk & 7) * 72 + (blk >> 3);
    int b = fs / 18, rr_ = fs % 18;
    int by = rr_ / 9, bx = rr_ % 9;
    int row0 = bx * 64, col0 = by * 128;

    unsigned short (*As)[72] = (unsigned short(*)[72])smem;               // 9216 B
    unsigned short (*Bs)[72] = (unsigned short(*)[72])(smem + 9216);      // 18432 B

    const int m16 = lane & 15, quad = lane >> 4;
    const int wm = wv >> 1, wn = wv & 1;
    const unsigned short* Ag = Abf + ((size_t)(b * LG + row0)) * CH;
    const unsigned short* Bg = Bbf + ((size_t)(b * LL + col0)) * CH;
    const int sr = tid >> 2, sq = tid & 3;   // A: 64 rows x 4 chunks of 16 shorts
    const int br = tid >> 1, bq = tid & 1;   // B: 128 rows x 2 chunks of 16 shorts

    f32x4 acc[2][4] = {};
    uint4 a0, a1, b0, b1, b2, b3;

    {
      const unsigned short* ap = Ag + (size_t)sr * CH + sq * 16;
      a0 = *(const uint4*)ap; a1 = *(const uint4*)(ap + 8);
      const unsigned short* bp = Bg + (size_t)br * CH + bq * 16;
      b0 = *(const uint4*)bp; b1 = *(const uint4*)(bp + 8);
      b2 = *(const uint4*)(bp + 32); b3 = *(const uint4*)(bp + 40);
    }

    #pragma unroll
    for (int t = 0; t < 8; ++t) {
      __syncthreads();
      *(uint4*)&As[sr][sq * 16]      = a0; *(uint4*)&As[sr][sq * 16 + 8]  = a1;
      *(uint4*)&Bs[br][bq * 16]      = b0; *(uint4*)&Bs[br][bq * 16 + 8]  = b1;
      *(uint4*)&Bs[br][bq * 16 + 32] = b2; *(uint4*)&Bs[br][bq * 16 + 40] = b3;
      __syncthreads();
      if (t < 7) {                        // issue next-step loads; fly under MFMA
        int k0 = (t + 1) * 64;
        const unsigned short* ap = Ag + (size_t)sr * CH + k0 + sq * 16;
        a0 = *(const uint4*)ap; a1 = *(const uint4*)(ap + 8);
        const unsigned short* bp = Bg + (size_t)br * CH + k0 + bq * 16;
        b0 = *(const uint4*)bp; b1 = *(const uint4*)(bp + 8);
        b2 = *(const uint4*)(bp + 32); b3 = *(const uint4*)(bp + 40);
      }
      #pragma unroll
      for (int kk = 0; kk < 64; kk += 32) {
        bf16x8 af0 = *(const bf16x8*)&As[wm * 32 + m16][kk + quad * 8];
        bf16x8 af1 = *(const bf16x8*)&As[wm * 32 + 16 + m16][kk + quad * 8];
        bf16x8 bfv[4];
        #pragma unroll
        for (int j = 0; j < 4; ++j)
          bfv[j] = *(const bf16x8*)&Bs[wn * 64 + j * 16 + m16][kk + quad * 8];
        #pragma unroll
        for (int j = 0; j < 4; ++j) {
          acc[0][j] = __builtin_amdgcn_mfma_f32_16x16x32_bf16(af0, bfv[j], acc[0][j], 0, 0, 0);
          acc[1][j] = __builtin_amdgcn_mfma_f32_16x16x32_bf16(af1, bfv[j], acc[1][j], 0, 0, 0);
        }
      }
    }

    float na[2][4], nb[4];
    #pragma unroll
    for (int i = 0; i < 2; ++i)
      #pragma unroll
      for (int r = 0; r < 4; ++r)
        na[i][r] = ng[b * LG + row0 + wm * 32 + i * 16 + quad * 4 + r];
    #pragma unroll
    for (int j = 0; j < 4; ++j)
      nb[j] = nl[b * LL + col0 + wn * 64 + j * 16 + m16];

    #pragma unroll
    for (int i = 0; i < 2; ++i) {
      #pragma unroll
      for (int r = 0; r < 4; ++r) {
        unsigned long long p = ~0ull;
        #pragma unroll
        for (int j = 0; j < 4; ++j) {
          float d = fmaxf(na[i][r] + nb[j] - 2.f * acc[i][j][r], 0.f);
          unsigned c = (unsigned)(col0 + wn * 64 + j * 16 + m16);
          unsigned long long pj = (((unsigned long long)__float_as_uint(d)) << 32) | c;
          p = pj < p ? pj : p;
        }
        #pragma unroll
        for (int s = 1; s < 16; s <<= 1) {
          unsigned long long q = __shfl_xor(p, s);
          p = q < p ? q : p;
        }
        if (m16 == 0)
          atomicMin(&rowNN[(size_t)b * LG + row0 + wm * 32 + i * 16 + quad * 4 + r], p);
      }
    }
    #pragma unroll
    for (int j = 0; j < 4; ++j) {
      unsigned long long p = ~0ull;
      #pragma unroll
      for (int i = 0; i < 2; ++i) {
        #pragma unroll
        for (int r = 0; r < 4; ++r) {
          float d = fmaxf(na[i][r] + nb[j] - 2.f * acc[i][j][r], 0.f);
          unsigned rg = (unsigned)(row0 + wm * 32 + i * 16 + quad * 4 + r);
          unsigned long long pr = (((unsigned long long)__float_as_uint(d)) << 32) | rg;
          p = pr < p ? pr : p;
        }
      }
      unsigned long long q = __shfl_xor(p, 16); p = q < p ? q : p;
      q = __shfl_xor(p, 32); p = q < p ? q : p;
      if (quad == 0)
        atomicMin(&colNN[(size_t)b * LL + col0 + wn * 64 + j * 16 + m16], p);
    }

    __syncthreads();
    __threadfence();
    if (tid == 0)
      __hip_atomic_fetch_add(&cnt[0], 1u, __ATOMIC_RELEASE, __HIP_MEMORY_SCOPE_AGENT);
    return;
  }

  // ---- gated sel V0/V1 + final ----
  TailSmem& ts = *reinterpret_cast<TailSmem*>(smem);
  if (tid == 0) {
    while (__hip_atomic_load(&cnt[0], __ATOMIC_ACQUIRE, __HIP_MEMORY_SCOPE_AGENT) < 576u)
      __builtin_amdgcn_s_sleep(8);
  }
  __syncthreads();

  int e = blk - 576;
  int b2 = e >> 1;
  if (e & 1) sel_case<1>(ts.sel, b2, zgf, zlf, gg, gl, rowNN, colNN, selsum);
  else       sel_case<0>(ts.sel, b2, zgf, zlf, gg, gl, rowNN, colNN, selsum);

  if (tid == 0) {
    __threadfence();
    unsigned r = __hip_atomic_fetch_add(&cnt[1], 1u, __ATOMIC_ACQ_REL, __HIP_MEMORY_SCOPE_AGENT);
    ts.isLast = (r == 63) ? 1 : 0;
  }
  __syncthreads();
  if (!ts.isLast) return;
  __threadfence();

  if (tid < 32) {
    #pragma unroll
    for (int zi = 0; zi < 2; ++zi) {
      float tp = 0.f;
      for (int bb = 0; bb < 32; ++bb) tp += S[zi * 1024 + tid * 32 + bb];
      ts.t[zi][tid] = tp * (1.f / 32.f);
    }
  }
  if (tid < 5) {
    double s = 0.0;
    for (int blk2 = 0; blk2 < 32; ++blk2) s += bsum[blk2 * 5 + tid];
    ts.sacc[tid] = s;
  }
  if (tid >= 8 && tid < 12) {
    int v = tid - 8;
    double s = 0.0;
    for (int bb = 0; bb < 32; ++bb) s += selsum[v * 32 + bb];
    ts.smf[v] = s;
  }
  __syncthreads();
  if (tid < 64) {
    double total[2];
    #pragma unroll
    for (int zi = 0; zi < 2; ++zi) {
      float u = 0.f;
      for (int bb = 0; bb < 32; ++bb) u += ts.t[zi][bb];
      u *= (1.f / 32.f);
      double s = 0.0;
      for (int e2 = tid; e2 < 1024; e2 += 64) {
        int p = e2 >> 5, q = e2 & 31;
        float G = S[zi * 1024 + e2] - ts.t[zi][p] - ts.t[zi][q] + u;
        s += (double)G * (double)G;
      }
      for (int off = 32; off; off >>= 1) s += __shfl_down(s, off);
      total[zi] = s;
    }
    if (tid == 0) {
      double inv_g = ts.sacc[0] / (32.0 * 8192.0);
      double v = 0.5 * (ts.sacc[1] + ts.sacc[2]) / 8192.0;
      double c = (total[0] - ts.sacc[3] + total[1] - ts.sacc[4]) / (961.0 * 8192.0);
      double gloss = 25.0 * inv_g + 25.0 * v + c;
      double mfg = ts.smf[0] / (32.0 * 20.0 * 512.0);
      double mfl = ts.smf[1] / (32.0 * 4.0 * 512.0);
      double mgg = ts.smf[2] / (32.0 * 20.0 * 512.0);
      double mgl = ts.smf[3] / (32.0 * 4.0 * 512.0);
      double lloss = 25.0 * (0.5 * (mfg + mfl) + 0.5 * (mgg + mgl));
      out[0] = (float)(0.25 * gloss + 0.75 * lloss);
    }
  }
}

extern "C" void kernel_launch(void* const* d_in, const int* in_sizes, int n_in,
                              void* d_out, int out_size, void* d_ws, size_t ws_size,
                              hipStream_t stream) {
  const float* zg  = (const float*)d_in[0];
  const float* zl  = (const float*)d_in[1];
  const float* zgf = (const float*)d_in[2];
  const float* zlf = (const float*)d_in[3];
  const float* gg  = (const float*)d_in[4];
  const float* glo = (const float*)d_in[5];

  char* ws = (char*)d_ws;
  float* S       = (float*)(ws + OFF_S);
  double* bsum   = (double*)(ws + OFF_BSUM);
  double* selsum = (double*)(ws + OFF_SELSUM);
  unsigned int* cnt = (unsigned int*)(ws + OFF_CNT);
  float* ng = (float*)(ws + OFF_NG);
  float* nl = (float*)(ws + OFF_NL);
  unsigned long long* rowNN = (unsigned long long*)(ws + OFF_RNN);
  unsigned long long* colNN = (unsigned long long*)(ws + OFF_CNN);
  unsigned short* Abf = (unsigned short*)(ws + OFF_ABF);
  unsigned short* Bbf = (unsigned short*)(ws + OFF_BBF);

  k_front2<<<NPREP + 32 + 1056 + 64, 256, 0, stream>>>(
      zg, zl, zgf, zlf, gg, glo, bsum, S, Abf, Bbf, ng, nl, rowNN, cnt, selsum);
  k_back<<<640, 256, 0, stream>>>(zgf, zlf, gg, glo, Abf, Bbf, ng, nl,
                                  rowNN, colNN, selsum, bsum, S, cnt, (float*)d_out);
}

// Round 4
// 176.129 us; speedup vs baseline: 1.2810x; 1.2810x over previous
//
#include <hip/hip_runtime.h>
#include <hip/hip_bf16.h>

#define BATCH 32
#define DZ    8192
#define LG    576
#define LL    256
#define CH    512

// ---- ws layout (byte offsets) ----
#define OFF_S      0                          // float[2*1024] raw Gram S
#define OFF_BSUM   8192                       // double[32*5]
#define OFF_SELSUM 9472                       // double[4*32]
#define OFF_CNT    10496                      // u32 selDone
#define OFF_NG     10560                      // float[BATCH*LG]
#define OFF_NL     84288                      // float[BATCH*LL]
#define OFF_RNN    117056                     // u64[BATCH*LG]
#define OFF_CNN    264512                     // u64[BATCH*LL]  (contiguous with RNN)
#define OFF_ABF    330048                     // bf16 bits [BATCH*LG*CH]
#define OFF_BBF    19204416                   // bf16 bits [BATCH*LL*CH]
#define WS_NEED    27593024

typedef __attribute__((ext_vector_type(8))) short bf16x8;
typedef __attribute__((ext_vector_type(4))) float f32x4;

__device__ __forceinline__ unsigned short f2bf(float x) {
  union { __hip_bfloat16 h; unsigned short u; } cv;
  cv.h = __float2bfloat16(x);
  return cv.u;
}

// -------- selection (unchanged math) --------
struct SelSmem {
  unsigned long long keys[LG];
  unsigned int nnm[LG];
  float cxy[2 * LG];
  unsigned int plist[40];
  unsigned int cnt;
  float fred[4];
};

template <int V>
__device__ __forceinline__ void sel_case(
    SelSmem& sm, int b,
    const float* __restrict__ zgf, const float* __restrict__ zlf,
    const float* __restrict__ gg, const float* __restrict__ gl,
    const unsigned long long* __restrict__ rowNN,
    const unsigned long long* __restrict__ colNN,
    double* __restrict__ selsum) {
  constexpr bool GDIR = (V == 0 || V == 2);
  constexpr int L1 = GDIR ? LG : LL;
  constexpr int L2 = GDIR ? LL : LG;
  constexpr int M  = GDIR ? 20 : 4;
  constexpr int NR = (L1 + 255) / 256;
  const float* fin  = GDIR ? zgf + (size_t)b * LG * CH : zlf + (size_t)b * LL * CH;
  const float* fcan = GDIR ? zlf + (size_t)b * LL * CH : zgf + (size_t)b * LG * CH;
  int tid = threadIdx.x, lane = tid & 63, wv = tid >> 6;
  if (tid == 0) sm.cnt = 0;

  if constexpr (V < 2) {
    const unsigned long long* src =
        (V == 0) ? rowNN + (size_t)b * LG : colNN + (size_t)b * LL;
    #pragma unroll
    for (int s = 0; s < NR; ++s) {
      int l = tid + s * 256;
      if (l < L1) {
        unsigned long long p = src[l];
        sm.keys[l] = (p & 0xFFFFFFFF00000000ull) | (unsigned)l;
        sm.nnm[l] = (unsigned)(p & 0xFFFFFFFFu);
      }
    }
  } else {
    const float* gin  = (V == 2) ? gg + (size_t)b * LG * 2 : gl + (size_t)b * LL * 2;
    const float* gcan = (V == 2) ? gl + (size_t)b * LL * 2 : gg + (size_t)b * LG * 2;
    #pragma unroll
    for (int s = 0; s < (2 * L2 + 255) / 256; ++s) {
      int i = tid + s * 256;
      if (i < 2 * L2) sm.cxy[i] = gcan[i];
    }
    __syncthreads();
    float x[NR], y[NR], bd[NR];
    unsigned bi[NR];
    #pragma unroll
    for (int s = 0; s < NR; ++s) {
      int l = tid + s * 256;
      x[s] = (l < L1) ? gin[2 * l] : 0.f;
      y[s] = (l < L1) ? gin[2 * l + 1] : 0.f;
      bd[s] = 3.4e38f; bi[s] = 0;
    }
    const float2* c2 = (const float2*)sm.cxy;
    for (int m2 = 0; m2 < L2; m2 += 8) {
      float2 cc[8];
      #pragma unroll
      for (int u = 0; u < 8; ++u) cc[u] = c2[m2 + u];
      #pragma unroll
      for (int u = 0; u < 8; ++u)
        #pragma unroll
        for (int s = 0; s < NR; ++s) {
          float dx = x[s] - cc[u].x, dy = y[s] - cc[u].y;
          float d2 = dx * dx + dy * dy;
          if (d2 < bd[s]) { bd[s] = d2; bi[s] = (unsigned)(m2 + u); }  // first-min
        }
    }
    #pragma unroll
    for (int s = 0; s < NR; ++s) {
      int l = tid + s * 256;
      if (l < L1) {
        sm.keys[l] = ((unsigned long long)__float_as_uint(bd[s]) << 32) | (unsigned)l;
        sm.nnm[l] = bi[s];
      }
    }
  }
  __syncthreads();

  unsigned long long myk[NR];
  int rk[NR];
  #pragma unroll
  for (int s = 0; s < NR; ++s) {
    int l = tid + s * 256;
    myk[s] = (l < L1) ? sm.keys[l] : ~0ull;
    rk[s] = 0;
  }
  for (int j = 0; j < L1; j += 8) {
    unsigned long long kk[8];
    #pragma unroll
    for (int u = 0; u < 8; ++u) kk[u] = sm.keys[j + u];
    #pragma unroll
    for (int u = 0; u < 8; ++u)
      #pragma unroll
      for (int s = 0; s < NR; ++s) rk[s] += (kk[u] < myk[s]) ? 1 : 0;
  }
  #pragma unroll
  for (int s = 0; s < NR; ++s) {
    int l = tid + s * 256;
    if (l < L1 && rk[s] < M) {
      unsigned slot = atomicAdd(&sm.cnt, 1u);
      sm.plist[2 * slot] = (unsigned)l;
      sm.plist[2 * slot + 1] = sm.nnm[l];
    }
  }
  __syncthreads();

  float part = 0.f;
  #pragma unroll
  for (int rr = 0; rr < M / 4; ++rr) {
    int r = wv + rr * 4;
    const float4* a4 = (const float4*)(fin + (size_t)sm.plist[2 * r] * CH);
    const float4* c4 = (const float4*)(fcan + (size_t)sm.plist[2 * r + 1] * CH);
    float4 xa = a4[lane * 2], xb = a4[lane * 2 + 1];
    float4 ya = c4[lane * 2], yb = c4[lane * 2 + 1];
    float d0 = xa.x - ya.x, d1 = xa.y - ya.y, d2 = xa.z - ya.z, d3 = xa.w - ya.w;
    float d4 = xb.x - yb.x, d5 = xb.y - yb.y, d6 = xb.z - yb.z, d7 = xb.w - yb.w;
    part += d0 * d0 + d1 * d1 + d2 * d2 + d3 * d3 +
            d4 * d4 + d5 * d5 + d6 * d6 + d7 * d7;
  }
  for (int s = 32; s; s >>= 1) part += __shfl_down(part, s);
  if (lane == 0) sm.fred[wv] = part;
  __syncthreads();
  if (tid == 0)
    selsum[V * 32 + b] = (double)(sm.fred[0] + sm.fred[1] + sm.fred[2] + sm.fred[3]);
}

// ==================== launch 1: prep + stats + gram + sel V2/V3 ====================
#define NPREP 6656
__global__ __launch_bounds__(256) void k_front2(
    const float* __restrict__ za, const float* __restrict__ zb,
    const float* __restrict__ zgf, const float* __restrict__ zlf,
    const float* __restrict__ gg, const float* __restrict__ gl,
    double* __restrict__ bsum, float* __restrict__ S,
    unsigned short* __restrict__ Abf, unsigned short* __restrict__ Bbf,
    float* __restrict__ ng, float* __restrict__ nl,
    unsigned long long* __restrict__ nnInit,
    unsigned int* __restrict__ cnt,
    double* __restrict__ selsum) {
  __shared__ __align__(16) char smem[12032];
  int tid = threadIdx.x, lane = tid & 63, wv = tid >> 6;
  int blk = blockIdx.x;

  if (blk < NPREP) {
    if (blk == 0 && tid == 0) cnt[0] = 0;     // tail done-counter reset
    int row = blk * 4 + wv;
    if (lane == 0) nnInit[row] = ~0ull;       // rowNN/colNN contiguous, 1:1 rows
    const float* src; unsigned short* dst; float* nrm;
    if (row < BATCH * LG) {
      src = zgf + (size_t)row * CH; dst = Abf + (size_t)row * CH; nrm = ng + row;
    } else {
      int rr = row - BATCH * LG;
      src = zlf + (size_t)rr * CH; dst = Bbf + (size_t)rr * CH; nrm = nl + rr;
    }
    const float4* s4 = (const float4*)src;
    float4 v0 = s4[lane * 2], v1 = s4[lane * 2 + 1];
    float ss = v0.x * v0.x + v0.y * v0.y + v0.z * v0.z + v0.w * v0.w +
               v1.x * v1.x + v1.y * v1.y + v1.z * v1.z + v1.w * v1.w;
    union { unsigned short h[8]; uint4 u; } pk;
    pk.h[0] = f2bf(v0.x); pk.h[1] = f2bf(v0.y); pk.h[2] = f2bf(v0.z); pk.h[3] = f2bf(v0.w);
    pk.h[4] = f2bf(v1.x); pk.h[5] = f2bf(v1.y); pk.h[6] = f2bf(v1.z); pk.h[7] = f2bf(v1.w);
    *(uint4*)(dst + lane * 8) = pk.u;
    for (int off = 32; off; off >>= 1) ss += __shfl_down(ss, off);
    if (lane == 0) *nrm = ss;
    return;
  }

  if (blk < NPREP + 32) {
    float (*sred)[5] = (float(*)[5])smem;
    int blkS = blk - NPREP;
    int i = blkS * 256 + tid;
    float sa = 0.f, qa = 0.f, sb = 0.f, qb = 0.f, si = 0.f;
    #pragma unroll 8
    for (int b = 0; b < BATCH; ++b) {
      float va = za[(size_t)b * DZ + i];
      float vb = zb[(size_t)b * DZ + i];
      sa += va; qa += va * va;
      sb += vb; qb += vb * vb;
      float d = va - vb; si += d * d;
    }
    float ssa = qa - sa * sa * (1.f / 32.f);
    float ssb = qb - sb * sb * (1.f / 32.f);
    float v0 = si;
    float v1 = fmaxf(0.f, 1.f - sqrtf(ssa * (1.f / 31.f) + 1e-4f));
    float v2 = fmaxf(0.f, 1.f - sqrtf(ssb * (1.f / 31.f) + 1e-4f));
    float v3 = ssa * ssa, v4 = ssb * ssb;
    for (int off = 32; off; off >>= 1) {
      v0 += __shfl_down(v0, off); v1 += __shfl_down(v1, off);
      v2 += __shfl_down(v2, off); v3 += __shfl_down(v3, off);
      v4 += __shfl_down(v4, off);
    }
    if (lane == 0) {
      sred[wv][0] = v0; sred[wv][1] = v1; sred[wv][2] = v2;
      sred[wv][3] = v3; sred[wv][4] = v4;
    }
    __syncthreads();
    if (tid < 5)
      bsum[blkS * 5 + tid] =
          (double)(sred[0][tid] + sred[1][tid] + sred[2][tid] + sred[3][tid]);
    return;
  }

  if (blk < NPREP + 32 + 1056) {
    float (*sred)[5] = (float(*)[5])smem;
    int e = blk - (NPREP + 32);               // 0..1055
    int zi = e >= 528; if (zi) e -= 528;
    const float* z = zi ? zb : za;
    float* Sz = S + zi * 1024;
    int p = 0, rem = e;
    while (rem >= 32 - p) { rem -= 32 - p; ++p; }
    int q = p + rem;
    const float4* zp = (const float4*)(z + (size_t)p * DZ);
    const float4* zq = (const float4*)(z + (size_t)q * DZ);
    float s = 0.f;
    #pragma unroll
    for (int ii = 0; ii < 8; ++ii) {
      int i = tid + ii * 256;
      float4 a = zp[i], bb = zq[i];
      s += a.x * bb.x + a.y * bb.y + a.z * bb.z + a.w * bb.w;
    }
    for (int off = 32; off; off >>= 1) s += __shfl_down(s, off);
    if (lane == 0) sred[wv][0] = s;
    __syncthreads();
    if (tid == 0) {
      float r = sred[0][0] + sred[1][0] + sred[2][0] + sred[3][0];
      Sz[p * 32 + q] = r;
      if (p != q) Sz[q * 32 + p] = r;
    }
    return;
  }

  // ---- grid-space sel V2/V3 (independent of feat NN) ----
  {
    SelSmem& sm = *reinterpret_cast<SelSmem*>(smem);
    int e = blk - (NPREP + 32 + 1056);
    int b2 = e >> 1;
    if (e & 1) sel_case<3>(sm, b2, zgf, zlf, gg, gl, nnInit, nnInit, selsum);
    else       sel_case<2>(sm, b2, zgf, zlf, gg, gl, nnInit, nnInit, selsum);
  }
}

// ==================== launch 2: feat MFMA (pipelined bf16, 64x128 tile) ====================
__global__ __launch_bounds__(256) void k_feat(
    const unsigned short* __restrict__ Abf, const unsigned short* __restrict__ Bbf,
    const float* __restrict__ ng, const float* __restrict__ nl,
    unsigned long long* __restrict__ rowNN, unsigned long long* __restrict__ colNN) {
  __shared__ __align__(16) char smem[27648];
  int tid = threadIdx.x, lane = tid & 63, wv = tid >> 6;
  int blk = blockIdx.x;

  // XCD swizzle (576 % 8 == 0)
  int fs = (blk & 7) * 72 + (blk >> 3);
  int b = fs / 18, rr_ = fs % 18;
  int by = rr_ / 9, bx = rr_ % 9;
  int row0 = bx * 64, col0 = by * 128;

  unsigned short (*As)[72] = (unsigned short(*)[72])smem;               // 9216 B
  unsigned short (*Bs)[72] = (unsigned short(*)[72])(smem + 9216);      // 18432 B

  const int m16 = lane & 15, quad = lane >> 4;
  const int wm = wv >> 1, wn = wv & 1;
  const unsigned short* Ag = Abf + ((size_t)(b * LG + row0)) * CH;
  const unsigned short* Bg = Bbf + ((size_t)(b * LL + col0)) * CH;
  const int sr = tid >> 2, sq = tid & 3;   // A: 64 rows x 4 chunks of 16 shorts
  const int br = tid >> 1, bq = tid & 1;   // B: 128 rows x 2 chunks of 16 shorts

  f32x4 acc[2][4] = {};
  uint4 a0, a1, b0, b1, b2, b3;

  {
    const unsigned short* ap = Ag + (size_t)sr * CH + sq * 16;
    a0 = *(const uint4*)ap; a1 = *(const uint4*)(ap + 8);
    const unsigned short* bp = Bg + (size_t)br * CH + bq * 16;
    b0 = *(const uint4*)bp; b1 = *(const uint4*)(bp + 8);
    b2 = *(const uint4*)(bp + 32); b3 = *(const uint4*)(bp + 40);
  }

  #pragma unroll
  for (int t = 0; t < 8; ++t) {
    __syncthreads();
    *(uint4*)&As[sr][sq * 16]      = a0; *(uint4*)&As[sr][sq * 16 + 8]  = a1;
    *(uint4*)&Bs[br][bq * 16]      = b0; *(uint4*)&Bs[br][bq * 16 + 8]  = b1;
    *(uint4*)&Bs[br][bq * 16 + 32] = b2; *(uint4*)&Bs[br][bq * 16 + 40] = b3;
    __syncthreads();
    if (t < 7) {                        // issue next-step loads; fly under MFMA
      int k0 = (t + 1) * 64;
      const unsigned short* ap = Ag + (size_t)sr * CH + k0 + sq * 16;
      a0 = *(const uint4*)ap; a1 = *(const uint4*)(ap + 8);
      const unsigned short* bp = Bg + (size_t)br * CH + k0 + bq * 16;
      b0 = *(const uint4*)bp; b1 = *(const uint4*)(bp + 8);
      b2 = *(const uint4*)(bp + 32); b3 = *(const uint4*)(bp + 40);
    }
    #pragma unroll
    for (int kk = 0; kk < 64; kk += 32) {
      bf16x8 af0 = *(const bf16x8*)&As[wm * 32 + m16][kk + quad * 8];
      bf16x8 af1 = *(const bf16x8*)&As[wm * 32 + 16 + m16][kk + quad * 8];
      bf16x8 bfv[4];
      #pragma unroll
      for (int j = 0; j < 4; ++j)
        bfv[j] = *(const bf16x8*)&Bs[wn * 64 + j * 16 + m16][kk + quad * 8];
      #pragma unroll
      for (int j = 0; j < 4; ++j) {
        acc[0][j] = __builtin_amdgcn_mfma_f32_16x16x32_bf16(af0, bfv[j], acc[0][j], 0, 0, 0);
        acc[1][j] = __builtin_amdgcn_mfma_f32_16x16x32_bf16(af1, bfv[j], acc[1][j], 0, 0, 0);
      }
    }
  }

  float na[2][4], nb[4];
  #pragma unroll
  for (int i = 0; i < 2; ++i)
    #pragma unroll
    for (int r = 0; r < 4; ++r)
      na[i][r] = ng[b * LG + row0 + wm * 32 + i * 16 + quad * 4 + r];
  #pragma unroll
  for (int j = 0; j < 4; ++j)
    nb[j] = nl[b * LL + col0 + wn * 64 + j * 16 + m16];

  #pragma unroll
  for (int i = 0; i < 2; ++i) {
    #pragma unroll
    for (int r = 0; r < 4; ++r) {
      unsigned long long p = ~0ull;
      #pragma unroll
      for (int j = 0; j < 4; ++j) {
        float d = fmaxf(na[i][r] + nb[j] - 2.f * acc[i][j][r], 0.f);
        unsigned c = (unsigned)(col0 + wn * 64 + j * 16 + m16);
        unsigned long long pj = (((unsigned long long)__float_as_uint(d)) << 32) | c;
        p = pj < p ? pj : p;
      }
      #pragma unroll
      for (int s = 1; s < 16; s <<= 1) {
        unsigned long long q = __shfl_xor(p, s);
        p = q < p ? q : p;
      }
      if (m16 == 0)
        atomicMin(&rowNN[(size_t)b * LG + row0 + wm * 32 + i * 16 + quad * 4 + r], p);
    }
  }
  #pragma unroll
  for (int j = 0; j < 4; ++j) {
    unsigned long long p = ~0ull;
    #pragma unroll
    for (int i = 0; i < 2; ++i) {
      #pragma unroll
      for (int r = 0; r < 4; ++r) {
        float d = fmaxf(na[i][r] + nb[j] - 2.f * acc[i][j][r], 0.f);
        unsigned rg = (unsigned)(row0 + wm * 32 + i * 16 + quad * 4 + r);
        unsigned long long pr = (((unsigned long long)__float_as_uint(d)) << 32) | rg;
        p = pr < p ? pr : p;
      }
    }
    unsigned long long q = __shfl_xor(p, 16); p = q < p ? q : p;
    q = __shfl_xor(p, 32); p = q < p ? q : p;
    if (quad == 0)
      atomicMin(&colNN[(size_t)b * LL + col0 + wn * 64 + j * 16 + m16], p);
  }
}

// ==================== launch 3: sel V0/V1 + last-block final ====================
struct TailSmem {
  SelSmem sel;
  float t[2][32];
  double sacc[5];
  double smf[4];
  int isLast;
};

__global__ __launch_bounds__(256) void k_tail(
    const float* __restrict__ zgf, const float* __restrict__ zlf,
    const float* __restrict__ gg, const float* __restrict__ gl,
    const unsigned long long* __restrict__ rowNN,
    const unsigned long long* __restrict__ colNN,
    double* __restrict__ selsum, const double* __restrict__ bsum,
    const float* __restrict__ S, unsigned int* __restrict__ doneCnt,
    float* __restrict__ out) {
  __shared__ TailSmem ts;
  int tid = threadIdx.x;
  int b = blockIdx.x >> 1, V = blockIdx.x & 1;
  if (V == 0) sel_case<0>(ts.sel, b, zgf, zlf, gg, gl, rowNN, colNN, selsum);
  else        sel_case<1>(ts.sel, b, zgf, zlf, gg, gl, rowNN, colNN, selsum);

  if (tid == 0) {
    __threadfence();
    unsigned r = atomicAdd(doneCnt, 1u);
    ts.isLast = (r == 63) ? 1 : 0;
  }
  __syncthreads();
  if (!ts.isLast) return;
  __threadfence();

  if (tid < 32) {
    #pragma unroll
    for (int zi = 0; zi < 2; ++zi) {
      float tp = 0.f;
      for (int bb = 0; bb < 32; ++bb) tp += S[zi * 1024 + tid * 32 + bb];
      ts.t[zi][tid] = tp * (1.f / 32.f);
    }
  }
  if (tid < 5) {
    double s = 0.0;
    for (int blk2 = 0; blk2 < 32; ++blk2) s += bsum[blk2 * 5 + tid];
    ts.sacc[tid] = s;
  }
  if (tid >= 8 && tid < 12) {
    int v = tid - 8;
    double s = 0.0;
    for (int bb = 0; bb < 32; ++bb) s += selsum[v * 32 + bb];
    ts.smf[v] = s;
  }
  __syncthreads();
  if (tid < 64) {
    double total[2];
    #pragma unroll
    for (int zi = 0; zi < 2; ++zi) {
      float u = 0.f;
      for (int bb = 0; bb < 32; ++bb) u += ts.t[zi][bb];
      u *= (1.f / 32.f);
      double s = 0.0;
      for (int e2 = tid; e2 < 1024; e2 += 64) {
        int p = e2 >> 5, q = e2 & 31;
        float G = S[zi * 1024 + e2] - ts.t[zi][p] - ts.t[zi][q] + u;
        s += (double)G * (double)G;
      }
      for (int off = 32; off; off >>= 1) s += __shfl_down(s, off);
      total[zi] = s;
    }
    if (tid == 0) {
      double inv_g = ts.sacc[0] / (32.0 * 8192.0);
      double v = 0.5 * (ts.sacc[1] + ts.sacc[2]) / 8192.0;
      double c = (total[0] - ts.sacc[3] + total[1] - ts.sacc[4]) / (961.0 * 8192.0);
      double gloss = 25.0 * inv_g + 25.0 * v + c;
      double mfg = ts.smf[0] / (32.0 * 20.0 * 512.0);
      double mfl = ts.smf[1] / (32.0 * 4.0 * 512.0);
      double mgg = ts.smf[2] / (32.0 * 20.0 * 512.0);
      double mgl = ts.smf[3] / (32.0 * 4.0 * 512.0);
      double lloss = 25.0 * (0.5 * (mfg + mfl) + 0.5 * (mgg + mgl));
      out[0] = (float)(0.25 * gloss + 0.75 * lloss);
    }
  }
}

extern "C" void kernel_launch(void* const* d_in, const int* in_sizes, int n_in,
                              void* d_out, int out_size, void* d_ws, size_t ws_size,
                              hipStream_t stream) {
  const float* zg  = (const float*)d_in[0];
  const float* zl  = (const float*)d_in[1];
  const float* zgf = (const float*)d_in[2];
  const float* zlf = (const float*)d_in[3];
  const float* gg  = (const float*)d_in[4];
  const float* glo = (const float*)d_in[5];

  char* ws = (char*)d_ws;
  float* S       = (float*)(ws + OFF_S);
  double* bsum   = (double*)(ws + OFF_BSUM);
  double* selsum = (double*)(ws + OFF_SELSUM);
  unsigned int* cnt = (unsigned int*)(ws + OFF_CNT);
  float* ng = (float*)(ws + OFF_NG);
  float* nl = (float*)(ws + OFF_NL);
  unsigned long long* rowNN = (unsigned long long*)(ws + OFF_RNN);
  unsigned long long* colNN = (unsigned long long*)(ws + OFF_CNN);
  unsigned short* Abf = (unsigned short*)(ws + OFF_ABF);
  unsigned short* Bbf = (unsigned short*)(ws + OFF_BBF);

  k_front2<<<NPREP + 32 + 1056 + 64, 256, 0, stream>>>(
      zg, zl, zgf, zlf, gg, glo, bsum, S, Abf, Bbf, ng, nl, rowNN, cnt, selsum);
  k_feat<<<576, 256, 0, stream>>>(Abf, Bbf, ng, nl, rowNN, colNN);
  k_tail<<<64, 256, 0, stream>>>(zgf, zlf, gg, glo, rowNN, colNN,
                                 selsum, bsum, S, cnt, (float*)d_out);
}

// Round 5
// 153.522 us; speedup vs baseline: 1.4696x; 1.1473x over previous
//
#include <hip/hip_runtime.h>
#include <hip/hip_bf16.h>

#define BATCH 32
#define DZ    8192
#define LG    576
#define LL    256
#define CH    512

// ---- ws layout (byte offsets) ----
#define OFF_S      0                          // float[2*1024] raw Gram S
#define OFF_BSUM   8192                       // double[32*5]
#define OFF_SELSUM 9472                       // double[4*32]
#define OFF_CNT    10496                      // u32 selDone
#define OFF_NG     10560                      // float[BATCH*LG]
#define OFF_NL     84288                      // float[BATCH*LL]
#define OFF_RNN    117056                     // u64[BATCH*LG]
#define OFF_CNN    264512                     // u64[BATCH*LL]  (contiguous with RNN)
#define OFF_ABF    330048                     // bf16 bits [BATCH*LG*CH]
#define OFF_BBF    19204416                   // bf16 bits [BATCH*LL*CH]
#define WS_NEED    27593024

typedef __attribute__((ext_vector_type(8))) short bf16x8;
typedef __attribute__((ext_vector_type(4))) float f32x4;

__device__ __forceinline__ unsigned short f2bf(float x) {
  union { __hip_bfloat16 h; unsigned short u; } cv;
  cv.h = __float2bfloat16(x);
  return cv.u;
}

// -------- selection (unchanged math) --------
struct SelSmem {
  unsigned long long keys[LG];
  unsigned int nnm[LG];
  float cxy[2 * LG];
  unsigned int plist[40];
  unsigned int cnt;
  float fred[4];
};

template <int V>
__device__ __forceinline__ void sel_case(
    SelSmem& sm, int b,
    const float* __restrict__ zgf, const float* __restrict__ zlf,
    const float* __restrict__ gg, const float* __restrict__ gl,
    const unsigned long long* __restrict__ rowNN,
    const unsigned long long* __restrict__ colNN,
    double* __restrict__ selsum) {
  constexpr bool GDIR = (V == 0 || V == 2);
  constexpr int L1 = GDIR ? LG : LL;
  constexpr int L2 = GDIR ? LL : LG;
  constexpr int M  = GDIR ? 20 : 4;
  constexpr int NR = (L1 + 255) / 256;
  const float* fin  = GDIR ? zgf + (size_t)b * LG * CH : zlf + (size_t)b * LL * CH;
  const float* fcan = GDIR ? zlf + (size_t)b * LL * CH : zgf + (size_t)b * LG * CH;
  int tid = threadIdx.x, lane = tid & 63, wv = tid >> 6;
  if (tid == 0) sm.cnt = 0;

  if constexpr (V < 2) {
    const unsigned long long* src =
        (V == 0) ? rowNN + (size_t)b * LG : colNN + (size_t)b * LL;
    #pragma unroll
    for (int s = 0; s < NR; ++s) {
      int l = tid + s * 256;
      if (l < L1) {
        unsigned long long p = src[l];
        sm.keys[l] = (p & 0xFFFFFFFF00000000ull) | (unsigned)l;
        sm.nnm[l] = (unsigned)(p & 0xFFFFFFFFu);
      }
    }
  } else {
    const float* gin  = (V == 2) ? gg + (size_t)b * LG * 2 : gl + (size_t)b * LL * 2;
    const float* gcan = (V == 2) ? gl + (size_t)b * LL * 2 : gg + (size_t)b * LG * 2;
    #pragma unroll
    for (int s = 0; s < (2 * L2 + 255) / 256; ++s) {
      int i = tid + s * 256;
      if (i < 2 * L2) sm.cxy[i] = gcan[i];
    }
    __syncthreads();
    float x[NR], y[NR], bd[NR];
    unsigned bi[NR];
    #pragma unroll
    for (int s = 0; s < NR; ++s) {
      int l = tid + s * 256;
      x[s] = (l < L1) ? gin[2 * l] : 0.f;
      y[s] = (l < L1) ? gin[2 * l + 1] : 0.f;
      bd[s] = 3.4e38f; bi[s] = 0;
    }
    const float2* c2 = (const float2*)sm.cxy;
    for (int m2 = 0; m2 < L2; m2 += 8) {
      float2 cc[8];
      #pragma unroll
      for (int u = 0; u < 8; ++u) cc[u] = c2[m2 + u];
      #pragma unroll
      for (int u = 0; u < 8; ++u)
        #pragma unroll
        for (int s = 0; s < NR; ++s) {
          float dx = x[s] - cc[u].x, dy = y[s] - cc[u].y;
          float d2 = dx * dx + dy * dy;
          if (d2 < bd[s]) { bd[s] = d2; bi[s] = (unsigned)(m2 + u); }  // first-min
        }
    }
    #pragma unroll
    for (int s = 0; s < NR; ++s) {
      int l = tid + s * 256;
      if (l < L1) {
        sm.keys[l] = ((unsigned long long)__float_as_uint(bd[s]) << 32) | (unsigned)l;
        sm.nnm[l] = bi[s];
      }
    }
  }
  __syncthreads();

  unsigned long long myk[NR];
  int rk[NR];
  #pragma unroll
  for (int s = 0; s < NR; ++s) {
    int l = tid + s * 256;
    myk[s] = (l < L1) ? sm.keys[l] : ~0ull;
    rk[s] = 0;
  }
  for (int j = 0; j < L1; j += 8) {
    unsigned long long kk[8];
    #pragma unroll
    for (int u = 0; u < 8; ++u) kk[u] = sm.keys[j + u];
    #pragma unroll
    for (int u = 0; u < 8; ++u)
      #pragma unroll
      for (int s = 0; s < NR; ++s) rk[s] += (kk[u] < myk[s]) ? 1 : 0;
  }
  #pragma unroll
  for (int s = 0; s < NR; ++s) {
    int l = tid + s * 256;
    if (l < L1 && rk[s] < M) {
      unsigned slot = atomicAdd(&sm.cnt, 1u);
      sm.plist[2 * slot] = (unsigned)l;
      sm.plist[2 * slot + 1] = sm.nnm[l];
    }
  }
  __syncthreads();

  float part = 0.f;
  #pragma unroll
  for (int rr = 0; rr < M / 4; ++rr) {
    int r = wv + rr * 4;
    const float4* a4 = (const float4*)(fin + (size_t)sm.plist[2 * r] * CH);
    const float4* c4 = (const float4*)(fcan + (size_t)sm.plist[2 * r + 1] * CH);
    float4 xa = a4[lane * 2], xb = a4[lane * 2 + 1];
    float4 ya = c4[lane * 2], yb = c4[lane * 2 + 1];
    float d0 = xa.x - ya.x, d1 = xa.y - ya.y, d2 = xa.z - ya.z, d3 = xa.w - ya.w;
    float d4 = xb.x - yb.x, d5 = xb.y - yb.y, d6 = xb.z - yb.z, d7 = xb.w - yb.w;
    part += d0 * d0 + d1 * d1 + d2 * d2 + d3 * d3 +
            d4 * d4 + d5 * d5 + d6 * d6 + d7 * d7;
  }
  for (int s = 32; s; s >>= 1) part += __shfl_down(part, s);
  if (lane == 0) sm.fred[wv] = part;
  __syncthreads();
  if (tid == 0)
    selsum[V * 32 + b] = (double)(sm.fred[0] + sm.fred[1] + sm.fred[2] + sm.fred[3]);
}

// ==================== launch 1: stats + gram + prep (R1-proven structure) ====================
// blk [0,32)       : per-feature stats   (blk 0 resets tail done-counter)
// blk [32,1088)    : raw Gram entries
// blk [1088,7744)  : prep (fp32->bf16, norms, NN init)
__global__ __launch_bounds__(256) void k_front(
    const float* __restrict__ za, const float* __restrict__ zb,
    const float* __restrict__ zgf, const float* __restrict__ zlf,
    double* __restrict__ bsum, float* __restrict__ S,
    unsigned short* __restrict__ Abf, unsigned short* __restrict__ Bbf,
    float* __restrict__ ng, float* __restrict__ nl,
    unsigned long long* __restrict__ nnInit,
    unsigned int* __restrict__ cnt) {
  __shared__ float sred[4][5];
  int tid = threadIdx.x, lane = tid & 63, wv = tid >> 6;
  int blk = blockIdx.x;

  if (blk >= 1088) {
    // ---- prep: 4 rows per block, one wave per row ----
    int row = (blk - 1088) * 4 + wv;
    if (lane == 0) nnInit[row] = ~0ull;       // rowNN/colNN contiguous, 1:1 rows
    const float* src; unsigned short* dst; float* nrm;
    if (row < BATCH * LG) {
      src = zgf + (size_t)row * CH; dst = Abf + (size_t)row * CH; nrm = ng + row;
    } else {
      int rr = row - BATCH * LG;
      src = zlf + (size_t)rr * CH; dst = Bbf + (size_t)rr * CH; nrm = nl + rr;
    }
    const float4* s4 = (const float4*)src;
    float4 v0 = s4[lane * 2], v1 = s4[lane * 2 + 1];
    float ss = v0.x * v0.x + v0.y * v0.y + v0.z * v0.z + v0.w * v0.w +
               v1.x * v1.x + v1.y * v1.y + v1.z * v1.z + v1.w * v1.w;
    union { unsigned short h[8]; uint4 u; } pk;
    pk.h[0] = f2bf(v0.x); pk.h[1] = f2bf(v0.y); pk.h[2] = f2bf(v0.z); pk.h[3] = f2bf(v0.w);
    pk.h[4] = f2bf(v1.x); pk.h[5] = f2bf(v1.y); pk.h[6] = f2bf(v1.z); pk.h[7] = f2bf(v1.w);
    *(uint4*)(dst + lane * 8) = pk.u;
    for (int off = 32; off; off >>= 1) ss += __shfl_down(ss, off);
    if (lane == 0) *nrm = ss;
    return;
  }

  if (blk < 32) {
    if (blk == 0 && tid == 0) cnt[0] = 0;
    int i = blk * 256 + tid;
    float sa = 0.f, qa = 0.f, sb = 0.f, qb = 0.f, si = 0.f;
    #pragma unroll 8
    for (int b = 0; b < BATCH; ++b) {
      float va = za[(size_t)b * DZ + i];
      float vb = zb[(size_t)b * DZ + i];
      sa += va; qa += va * va;
      sb += vb; qb += vb * vb;
      float d = va - vb; si += d * d;
    }
    float ssa = qa - sa * sa * (1.f / 32.f);
    float ssb = qb - sb * sb * (1.f / 32.f);
    float v0 = si;
    float v1 = fmaxf(0.f, 1.f - sqrtf(ssa * (1.f / 31.f) + 1e-4f));
    float v2 = fmaxf(0.f, 1.f - sqrtf(ssb * (1.f / 31.f) + 1e-4f));
    float v3 = ssa * ssa, v4 = ssb * ssb;
    for (int off = 32; off; off >>= 1) {
      v0 += __shfl_down(v0, off); v1 += __shfl_down(v1, off);
      v2 += __shfl_down(v2, off); v3 += __shfl_down(v3, off);
      v4 += __shfl_down(v4, off);
    }
    if (lane == 0) {
      sred[wv][0] = v0; sred[wv][1] = v1; sred[wv][2] = v2;
      sred[wv][3] = v3; sred[wv][4] = v4;
    }
    __syncthreads();
    if (tid < 5)
      bsum[blk * 5 + tid] =
          (double)(sred[0][tid] + sred[1][tid] + sred[2][tid] + sred[3][tid]);
  } else {
    int e = blk - 32;                         // 0..1055
    int zi = e >= 528; if (zi) e -= 528;
    const float* z = zi ? zb : za;
    float* Sz = S + zi * 1024;
    int p = 0, rem = e;
    while (rem >= 32 - p) { rem -= 32 - p; ++p; }
    int q = p + rem;
    const float4* zp = (const float4*)(z + (size_t)p * DZ);
    const float4* zq = (const float4*)(z + (size_t)q * DZ);
    float s = 0.f;
    #pragma unroll
    for (int ii = 0; ii < 8; ++ii) {
      int i = tid + ii * 256;
      float4 a = zp[i], bb = zq[i];
      s += a.x * bb.x + a.y * bb.y + a.z * bb.z + a.w * bb.w;
    }
    for (int off = 32; off; off >>= 1) s += __shfl_down(s, off);
    if (lane == 0) sred[wv][0] = s;
    __syncthreads();
    if (tid == 0) {
      float r = sred[0][0] + sred[1][0] + sred[2][0] + sred[3][0];
      Sz[p * 32 + q] = r;
      if (p != q) Sz[q * 32 + p] = r;
    }
  }
}

// ==================== launch 2: sel V2/V3 (first) + feat MFMA ====================
// blk [0,64)   : grid-space sel V2/V3 (longest serial blocks -> start first)
// blk [64,640) : feat MFMA (pipelined bf16, 64x128 tile, XCD-swizzled)
__global__ __launch_bounds__(256) void k_mid(
    const float* __restrict__ zgf, const float* __restrict__ zlf,
    const float* __restrict__ gg, const float* __restrict__ gl,
    const unsigned short* __restrict__ Abf, const unsigned short* __restrict__ Bbf,
    const float* __restrict__ ng, const float* __restrict__ nl,
    unsigned long long* __restrict__ rowNN, unsigned long long* __restrict__ colNN,
    double* __restrict__ selsum) {
  __shared__ __align__(16) char smem[27648];
  int tid = threadIdx.x, lane = tid & 63, wv = tid >> 6;
  int blk = blockIdx.x;

  if (blk < 64) {
    SelSmem& sm = *reinterpret_cast<SelSmem*>(smem);
    int b2 = blk >> 1;
    if (blk & 1) sel_case<3>(sm, b2, zgf, zlf, gg, gl, rowNN, colNN, selsum);
    else         sel_case<2>(sm, b2, zgf, zlf, gg, gl, rowNN, colNN, selsum);
    return;
  }

  int fblk = blk - 64;
  // XCD swizzle (576 % 8 == 0)
  int fs = (fblk & 7) * 72 + (fblk >> 3);
  int b = fs / 18, rr_ = fs % 18;
  int by = rr_ / 9, bx = rr_ % 9;
  int row0 = bx * 64, col0 = by * 128;

  unsigned short (*As)[72] = (unsigned short(*)[72])smem;               // 9216 B
  unsigned short (*Bs)[72] = (unsigned short(*)[72])(smem + 9216);      // 18432 B

  const int m16 = lane & 15, quad = lane >> 4;
  const int wm = wv >> 1, wn = wv & 1;
  const unsigned short* Ag = Abf + ((size_t)(b * LG + row0)) * CH;
  const unsigned short* Bg = Bbf + ((size_t)(b * LL + col0)) * CH;
  const int sr = tid >> 2, sq = tid & 3;   // A: 64 rows x 4 chunks of 16 shorts
  const int br = tid >> 1, bq = tid & 1;   // B: 128 rows x 2 chunks of 16 shorts

  f32x4 acc[2][4] = {};
  uint4 a0, a1, b0, b1, b2, b3;

  {
    const unsigned short* ap = Ag + (size_t)sr * CH + sq * 16;
    a0 = *(const uint4*)ap; a1 = *(const uint4*)(ap + 8);
    const unsigned short* bp = Bg + (size_t)br * CH + bq * 16;
    b0 = *(const uint4*)bp; b1 = *(const uint4*)(bp + 8);
    b2 = *(const uint4*)(bp + 32); b3 = *(const uint4*)(bp + 40);
  }

  #pragma unroll
  for (int t = 0; t < 8; ++t) {
    __syncthreads();
    *(uint4*)&As[sr][sq * 16]      = a0; *(uint4*)&As[sr][sq * 16 + 8]  = a1;
    *(uint4*)&Bs[br][bq * 16]      = b0; *(uint4*)&Bs[br][bq * 16 + 8]  = b1;
    *(uint4*)&Bs[br][bq * 16 + 32] = b2; *(uint4*)&Bs[br][bq * 16 + 40] = b3;
    __syncthreads();
    if (t < 7) {                        // issue next-step loads; fly under MFMA
      int k0 = (t + 1) * 64;
      const unsigned short* ap = Ag + (size_t)sr * CH + k0 + sq * 16;
      a0 = *(const uint4*)ap; a1 = *(const uint4*)(ap + 8);
      const unsigned short* bp = Bg + (size_t)br * CH + k0 + bq * 16;
      b0 = *(const uint4*)bp; b1 = *(const uint4*)(bp + 8);
      b2 = *(const uint4*)(bp + 32); b3 = *(const uint4*)(bp + 40);
    }
    #pragma unroll
    for (int kk = 0; kk < 64; kk += 32) {
      bf16x8 af0 = *(const bf16x8*)&As[wm * 32 + m16][kk + quad * 8];
      bf16x8 af1 = *(const bf16x8*)&As[wm * 32 + 16 + m16][kk + quad * 8];
      bf16x8 bfv[4];
      #pragma unroll
      for (int j = 0; j < 4; ++j)
        bfv[j] = *(const bf16x8*)&Bs[wn * 64 + j * 16 + m16][kk + quad * 8];
      #pragma unroll
      for (int j = 0; j < 4; ++j) {
        acc[0][j] = __builtin_amdgcn_mfma_f32_16x16x32_bf16(af0, bfv[j], acc[0][j], 0, 0, 0);
        acc[1][j] = __builtin_amdgcn_mfma_f32_16x16x32_bf16(af1, bfv[j], acc[1][j], 0, 0, 0);
      }
    }
  }

  float na[2][4], nb[4];
  #pragma unroll
  for (int i = 0; i < 2; ++i)
    #pragma unroll
    for (int r = 0; r < 4; ++r)
      na[i][r] = ng[b * LG + row0 + wm * 32 + i * 16 + quad * 4 + r];
  #pragma unroll
  for (int j = 0; j < 4; ++j)
    nb[j] = nl[b * LL + col0 + wn * 64 + j * 16 + m16];

  #pragma unroll
  for (int i = 0; i < 2; ++i) {
    #pragma unroll
    for (int r = 0; r < 4; ++r) {
      unsigned long long p = ~0ull;
      #pragma unroll
      for (int j = 0; j < 4; ++j) {
        float d = fmaxf(na[i][r] + nb[j] - 2.f * acc[i][j][r], 0.f);
        unsigned c = (unsigned)(col0 + wn * 64 + j * 16 + m16);
        unsigned long long pj = (((unsigned long long)__float_as_uint(d)) << 32) | c;
        p = pj < p ? pj : p;
      }
      #pragma unroll
      for (int s = 1; s < 16; s <<= 1) {
        unsigned long long q = __shfl_xor(p, s);
        p = q < p ? q : p;
      }
      if (m16 == 0)
        atomicMin(&rowNN[(size_t)b * LG + row0 + wm * 32 + i * 16 + quad * 4 + r], p);
    }
  }
  #pragma unroll
  for (int j = 0; j < 4; ++j) {
    unsigned long long p = ~0ull;
    #pragma unroll
    for (int i = 0; i < 2; ++i) {
      #pragma unroll
      for (int r = 0; r < 4; ++r) {
        float d = fmaxf(na[i][r] + nb[j] - 2.f * acc[i][j][r], 0.f);
        unsigned rg = (unsigned)(row0 + wm * 32 + i * 16 + quad * 4 + r);
        unsigned long long pr = (((unsigned long long)__float_as_uint(d)) << 32) | rg;
        p = pr < p ? pr : p;
      }
    }
    unsigned long long q = __shfl_xor(p, 16); p = q < p ? q : p;
    q = __shfl_xor(p, 32); p = q < p ? q : p;
    if (quad == 0)
      atomicMin(&colNN[(size_t)b * LL + col0 + wn * 64 + j * 16 + m16], p);
  }
}

// ==================== launch 3: sel V0/V1 + last-block final ====================
struct TailSmem {
  SelSmem sel;
  float t[2][32];
  double sacc[5];
  double smf[4];
  int isLast;
};

__global__ __launch_bounds__(256) void k_tail(
    const float* __restrict__ zgf, const float* __restrict__ zlf,
    const float* __restrict__ gg, const float* __restrict__ gl,
    const unsigned long long* __restrict__ rowNN,
    const unsigned long long* __restrict__ colNN,
    double* __restrict__ selsum, const double* __restrict__ bsum,
    const float* __restrict__ S, unsigned int* __restrict__ doneCnt,
    float* __restrict__ out) {
  __shared__ TailSmem ts;
  int tid = threadIdx.x;
  int b = blockIdx.x >> 1, V = blockIdx.x & 1;
  if (V == 0) sel_case<0>(ts.sel, b, zgf, zlf, gg, gl, rowNN, colNN, selsum);
  else        sel_case<1>(ts.sel, b, zgf, zlf, gg, gl, rowNN, colNN, selsum);

  if (tid == 0) {
    __threadfence();
    unsigned r = atomicAdd(doneCnt, 1u);
    ts.isLast = (r == 63) ? 1 : 0;
  }
  __syncthreads();
  if (!ts.isLast) return;
  __threadfence();

  if (tid < 32) {
    #pragma unroll
    for (int zi = 0; zi < 2; ++zi) {
      float tp = 0.f;
      for (int bb = 0; bb < 32; ++bb) tp += S[zi * 1024 + tid * 32 + bb];
      ts.t[zi][tid] = tp * (1.f / 32.f);
    }
  }
  if (tid < 5) {
    double s = 0.0;
    for (int blk2 = 0; blk2 < 32; ++blk2) s += bsum[blk2 * 5 + tid];
    ts.sacc[tid] = s;
  }
  if (tid >= 8 && tid < 12) {
    int v = tid - 8;
    double s = 0.0;
    for (int bb = 0; bb < 32; ++bb) s += selsum[v * 32 + bb];
    ts.smf[v] = s;
  }
  __syncthreads();
  if (tid < 64) {
    double total[2];
    #pragma unroll
    for (int zi = 0; zi < 2; ++zi) {
      float u = 0.f;
      for (int bb = 0; bb < 32; ++bb) u += ts.t[zi][bb];
      u *= (1.f / 32.f);
      double s = 0.0;
      for (int e2 = tid; e2 < 1024; e2 += 64) {
        int p = e2 >> 5, q = e2 & 31;
        float G = S[zi * 1024 + e2] - ts.t[zi][p] - ts.t[zi][q] + u;
        s += (double)G * (double)G;
      }
      for (int off = 32; off; off >>= 1) s += __shfl_down(s, off);
      total[zi] = s;
    }
    if (tid == 0) {
      double inv_g = ts.sacc[0] / (32.0 * 8192.0);
      double v = 0.5 * (ts.sacc[1] + ts.sacc[2]) / 8192.0;
      double c = (total[0] - ts.sacc[3] + total[1] - ts.sacc[4]) / (961.0 * 8192.0);
      double gloss = 25.0 * inv_g + 25.0 * v + c;
      double mfg = ts.smf[0] / (32.0 * 20.0 * 512.0);
      double mfl = ts.smf[1] / (32.0 * 4.0 * 512.0);
      double mgg = ts.smf[2] / (32.0 * 20.0 * 512.0);
      double mgl = ts.smf[3] / (32.0 * 4.0 * 512.0);
      double lloss = 25.0 * (0.5 * (mfg + mfl) + 0.5 * (mgg + mgl));
      out[0] = (float)(0.25 * gloss + 0.75 * lloss);
    }
  }
}

extern "C" void kernel_launch(void* const* d_in, const int* in_sizes, int n_in,
                              void* d_out, int out_size, void* d_ws, size_t ws_size,
                              hipStream_t stream) {
  const float* zg  = (const float*)d_in[0];
  const float* zl  = (const float*)d_in[1];
  const float* zgf = (const float*)d_in[2];
  const float* zlf = (const float*)d_in[3];
  const float* gg  = (const float*)d_in[4];
  const float* glo = (const float*)d_in[5];

  char* ws = (char*)d_ws;
  float* S       = (float*)(ws + OFF_S);
  double* bsum   = (double*)(ws + OFF_BSUM);
  double* selsum = (double*)(ws + OFF_SELSUM);
  unsigned int* cnt = (unsigned int*)(ws + OFF_CNT);
  float* ng = (float*)(ws + OFF_NG);
  float* nl = (float*)(ws + OFF_NL);
  unsigned long long* rowNN = (unsigned long long*)(ws + OFF_RNN);
  unsigned long long* colNN = (unsigned long long*)(ws + OFF_CNN);
  unsigned short* Abf = (unsigned short*)(ws + OFF_ABF);
  unsigned short* Bbf = (unsigned short*)(ws + OFF_BBF);

  k_front<<<1088 + 6656, 256, 0, stream>>>(
      zg, zl, zgf, zlf, bsum, S, Abf, Bbf, ng, nl, rowNN, cnt);
  k_mid<<<64 + 576, 256, 0, stream>>>(
      zgf, zlf, gg, glo, Abf, Bbf, ng, nl, rowNN, colNN, selsum);
  k_tail<<<64, 256, 0, stream>>>(zgf, zlf, gg, glo, rowNN, colNN,
                                 selsum, bsum, S, cnt, (float*)d_out);
}

// Round 6
// 138.479 us; speedup vs baseline: 1.6293x; 1.1086x over previous
//
#include <hip/hip_runtime.h>
#include <hip/hip_bf16.h>

#define BATCH 32
#define DZ    8192
#define LG    576
#define LL    256
#define CH    512

// ---- ws layout (byte offsets) ----
#define OFF_S      0                          // float[2*1024] raw Gram S
#define OFF_BSUM   8192                       // double[32*5]
#define OFF_SELSUM 9472                       // double[4*32]
#define OFF_CNT    10496                      // u32 selDone
#define OFF_RNP    10560                      // u64[BATCH*LG*2]  row-NN partials
#define OFF_CNP    305472                     // u64[BATCH*LL*9]  col-NN partials
#define WS_NEED    895296

typedef __attribute__((ext_vector_type(8))) short bf16x8;
typedef __attribute__((ext_vector_type(4))) float f32x4;

__device__ __forceinline__ unsigned short f2bf(float x) {
  union { __hip_bfloat16 h; unsigned short u; } cv;
  cv.h = __float2bfloat16(x);
  return cv.u;
}

__device__ __forceinline__ uint4 pack8(float4 lo, float4 hi) {
  union { unsigned short h[8]; uint4 u; } pk;
  pk.h[0] = f2bf(lo.x); pk.h[1] = f2bf(lo.y); pk.h[2] = f2bf(lo.z); pk.h[3] = f2bf(lo.w);
  pk.h[4] = f2bf(hi.x); pk.h[5] = f2bf(hi.y); pk.h[6] = f2bf(hi.z); pk.h[7] = f2bf(hi.w);
  return pk.u;
}

__device__ __forceinline__ float dot4(float4 v) {
  return v.x * v.x + v.y * v.y + v.z * v.z + v.w * v.w;
}

// -------- selection --------
struct SelSmem {
  unsigned long long keys[LG];
  unsigned int nnm[LG];
  float cxy[2 * LG];
  unsigned int plist[40];
  unsigned int cnt;
  float fred[4];
};

// V0/V1: feature NN from partials (x2 / x9).  V2/V3: grid NN.
template <int V>
__device__ __forceinline__ void sel_case(
    SelSmem& sm, int b,
    const float* __restrict__ zgf, const float* __restrict__ zlf,
    const float* __restrict__ gg, const float* __restrict__ gl,
    const unsigned long long* __restrict__ rowNNp,
    const unsigned long long* __restrict__ colNNp,
    double* __restrict__ selsum) {
  constexpr bool GDIR = (V == 0 || V == 2);
  constexpr int L1 = GDIR ? LG : LL;
  constexpr int L2 = GDIR ? LL : LG;
  constexpr int M  = GDIR ? 20 : 4;
  constexpr int NR = (L1 + 255) / 256;
  const float* fin  = GDIR ? zgf + (size_t)b * LG * CH : zlf + (size_t)b * LL * CH;
  const float* fcan = GDIR ? zlf + (size_t)b * LL * CH : zgf + (size_t)b * LG * CH;
  int tid = threadIdx.x, lane = tid & 63, wv = tid >> 6;
  if (tid == 0) sm.cnt = 0;

  if constexpr (V < 2) {
    constexpr int P = (V == 0) ? 2 : 9;
    const unsigned long long* src =
        (V == 0) ? rowNNp + (size_t)b * LG * 2 : colNNp + (size_t)b * LL * 9;
    #pragma unroll
    for (int s = 0; s < NR; ++s) {
      int l = tid + s * 256;
      if (l < L1) {
        const unsigned long long* q = src + (size_t)l * P;
        unsigned long long p = q[0];
        #pragma unroll
        for (int u = 1; u < P; ++u) { unsigned long long t2 = q[u]; p = t2 < p ? t2 : p; }
        sm.keys[l] = (p & 0xFFFFFFFF00000000ull) | (unsigned)l;
        sm.nnm[l] = (unsigned)(p & 0xFFFFFFFFu);
      }
    }
  } else {
    const float* gin  = (V == 2) ? gg + (size_t)b * LG * 2 : gl + (size_t)b * LL * 2;
    const float* gcan = (V == 2) ? gl + (size_t)b * LL * 2 : gg + (size_t)b * LG * 2;
    #pragma unroll
    for (int s = 0; s < (2 * L2 + 255) / 256; ++s) {
      int i = tid + s * 256;
      if (i < 2 * L2) sm.cxy[i] = gcan[i];
    }
    __syncthreads();
    float x[NR], y[NR], bd[NR];
    unsigned bi[NR];
    #pragma unroll
    for (int s = 0; s < NR; ++s) {
      int l = tid + s * 256;
      x[s] = (l < L1) ? gin[2 * l] : 0.f;
      y[s] = (l < L1) ? gin[2 * l + 1] : 0.f;
      bd[s] = 3.4e38f; bi[s] = 0;
    }
    const float2* c2 = (const float2*)sm.cxy;
    for (int m2 = 0; m2 < L2; m2 += 8) {
      float2 cc[8];
      #pragma unroll
      for (int u = 0; u < 8; ++u) cc[u] = c2[m2 + u];
      #pragma unroll
      for (int u = 0; u < 8; ++u)
        #pragma unroll
        for (int s = 0; s < NR; ++s) {
          float dx = x[s] - cc[u].x, dy = y[s] - cc[u].y;
          float d2 = dx * dx + dy * dy;
          if (d2 < bd[s]) { bd[s] = d2; bi[s] = (unsigned)(m2 + u); }  // first-min
        }
    }
    #pragma unroll
    for (int s = 0; s < NR; ++s) {
      int l = tid + s * 256;
      if (l < L1) {
        sm.keys[l] = ((unsigned long long)__float_as_uint(bd[s]) << 32) | (unsigned)l;
        sm.nnm[l] = bi[s];
      }
    }
  }
  __syncthreads();

  unsigned long long myk[NR];
  int rk[NR];
  #pragma unroll
  for (int s = 0; s < NR; ++s) {
    int l = tid + s * 256;
    myk[s] = (l < L1) ? sm.keys[l] : ~0ull;
    rk[s] = 0;
  }
  for (int j = 0; j < L1; j += 8) {
    unsigned long long kk[8];
    #pragma unroll
    for (int u = 0; u < 8; ++u) kk[u] = sm.keys[j + u];
    #pragma unroll
    for (int u = 0; u < 8; ++u)
      #pragma unroll
      for (int s = 0; s < NR; ++s) rk[s] += (kk[u] < myk[s]) ? 1 : 0;
  }
  #pragma unroll
  for (int s = 0; s < NR; ++s) {
    int l = tid + s * 256;
    if (l < L1 && rk[s] < M) {
      unsigned slot = atomicAdd(&sm.cnt, 1u);
      sm.plist[2 * slot] = (unsigned)l;
      sm.plist[2 * slot + 1] = sm.nnm[l];
    }
  }
  __syncthreads();

  float part = 0.f;
  #pragma unroll
  for (int rr = 0; rr < M / 4; ++rr) {
    int r = wv + rr * 4;
    const float4* a4 = (const float4*)(fin + (size_t)sm.plist[2 * r] * CH);
    const float4* c4 = (const float4*)(fcan + (size_t)sm.plist[2 * r + 1] * CH);
    float4 xa = a4[lane * 2], xb = a4[lane * 2 + 1];
    float4 ya = c4[lane * 2], yb = c4[lane * 2 + 1];
    float d0 = xa.x - ya.x, d1 = xa.y - ya.y, d2 = xa.z - ya.z, d3 = xa.w - ya.w;
    float d4 = xb.x - yb.x, d5 = xb.y - yb.y, d6 = xb.z - yb.z, d7 = xb.w - yb.w;
    part += d0 * d0 + d1 * d1 + d2 * d2 + d3 * d3 +
            d4 * d4 + d5 * d5 + d6 * d6 + d7 * d7;
  }
  for (int s = 32; s; s >>= 1) part += __shfl_down(part, s);
  if (lane == 0) sm.fred[wv] = part;
  __syncthreads();
  if (tid == 0)
    selsum[V * 32 + b] = (double)(sm.fred[0] + sm.fred[1] + sm.fred[2] + sm.fred[3]);
}

// ==================== launch A ====================
// blk [0,64)      : grid-space sel V2/V3 (longest serial blocks -> dispatched first)
// blk [64,640)    : feat MFMA, fp32-direct staging (prefetched), in-kernel norms,
//                   partial-NN plain stores (no init needed)
// blk [640,1696)  : raw Gram entries
// blk [1696,1728) : per-feature stats  (blk 1696 resets tail done-counter)
__global__ __launch_bounds__(256) void k_megaA(
    const float* __restrict__ za, const float* __restrict__ zb,
    const float* __restrict__ zgf, const float* __restrict__ zlf,
    const float* __restrict__ gg, const float* __restrict__ gl,
    double* __restrict__ bsum, float* __restrict__ S,
    unsigned long long* __restrict__ rowNNp, unsigned long long* __restrict__ colNNp,
    double* __restrict__ selsum, unsigned int* __restrict__ cnt) {
  __shared__ __align__(16) char smem[28416];
  int tid = threadIdx.x, lane = tid & 63, wv = tid >> 6;
  int blk = blockIdx.x;

  if (blk < 64) {
    SelSmem& sm = *reinterpret_cast<SelSmem*>(smem);
    int b2 = blk >> 1;
    if (blk & 1) sel_case<3>(sm, b2, zgf, zlf, gg, gl, rowNNp, colNNp, selsum);
    else         sel_case<2>(sm, b2, zgf, zlf, gg, gl, rowNNp, colNNp, selsum);
    return;
  }

  if (blk < 640) {
    // ---- feat: 64x128 tile, fp32 loads -> bf16 LDS, software-pipelined ----
    int fblk = blk - 64;
    int fs = (fblk & 7) * 72 + (fblk >> 3);   // XCD swizzle (576 % 8 == 0)
    int b = fs / 18, rr_ = fs % 18;
    int by = rr_ / 9, bx = rr_ % 9;
    int row0 = bx * 64, col0 = by * 128;

    unsigned short (*As)[72] = (unsigned short(*)[72])smem;               // 9216 B
    unsigned short (*Bs)[72] = (unsigned short(*)[72])(smem + 9216);      // 18432 B
    float* Asn = (float*)(smem + 27648);                                  // 256 B
    float* Bsn = (float*)(smem + 27904);                                  // 512 B

    const int m16 = lane & 15, quad = lane >> 4;
    const int wm = wv >> 1, wn = wv & 1;
    const float* Ag = zgf + ((size_t)(b * LG + row0)) * CH;
    const float* Bg = zlf + ((size_t)(b * LL + col0)) * CH;
    const int sr = tid >> 2, sq = tid & 3;   // A: 64 rows x 16-float chunks
    const int br = tid >> 1, bq = tid & 1;   // B: 128 rows x 2x16-float chunks

    f32x4 acc[2][4] = {};
    float ssA = 0.f, ssB = 0.f;
    float4 a0, a1, a2, a3, b0, b1, b2, b3, b4, b5, b6, b7;

    {
      const float* ap = Ag + (size_t)sr * CH + sq * 16;
      a0 = *(const float4*)(ap);      a1 = *(const float4*)(ap + 4);
      a2 = *(const float4*)(ap + 8);  a3 = *(const float4*)(ap + 12);
      const float* bp = Bg + (size_t)br * CH + bq * 16;
      b0 = *(const float4*)(bp);      b1 = *(const float4*)(bp + 4);
      b2 = *(const float4*)(bp + 8);  b3 = *(const float4*)(bp + 12);
      b4 = *(const float4*)(bp + 32); b5 = *(const float4*)(bp + 36);
      b6 = *(const float4*)(bp + 40); b7 = *(const float4*)(bp + 44);
    }

    #pragma unroll
    for (int t = 0; t < 8; ++t) {
      __syncthreads();
      // consume current regs: pack -> LDS, accumulate norms (frees regs for prefetch)
      *(uint4*)&As[sr][sq * 16]      = pack8(a0, a1);
      *(uint4*)&As[sr][sq * 16 + 8]  = pack8(a2, a3);
      *(uint4*)&Bs[br][bq * 16]      = pack8(b0, b1);
      *(uint4*)&Bs[br][bq * 16 + 8]  = pack8(b2, b3);
      *(uint4*)&Bs[br][bq * 16 + 32] = pack8(b4, b5);
      *(uint4*)&Bs[br][bq * 16 + 40] = pack8(b6, b7);
      ssA += dot4(a0) + dot4(a1) + dot4(a2) + dot4(a3);
      ssB += dot4(b0) + dot4(b1) + dot4(b2) + dot4(b3) +
             dot4(b4) + dot4(b5) + dot4(b6) + dot4(b7);
      __syncthreads();
      if (t < 7) {                        // issue next-step loads; fly under MFMA
        int k0 = (t + 1) * 64;
        const float* ap = Ag + (size_t)sr * CH + k0 + sq * 16;
        a0 = *(const float4*)(ap);      a1 = *(const float4*)(ap + 4);
        a2 = *(const float4*)(ap + 8);  a3 = *(const float4*)(ap + 12);
        const float* bp = Bg + (size_t)br * CH + k0 + bq * 16;
        b0 = *(const float4*)(bp);      b1 = *(const float4*)(bp + 4);
        b2 = *(const float4*)(bp + 8);  b3 = *(const float4*)(bp + 12);
        b4 = *(const float4*)(bp + 32); b5 = *(const float4*)(bp + 36);
        b6 = *(const float4*)(bp + 40); b7 = *(const float4*)(bp + 44);
      }
      #pragma unroll
      for (int kk = 0; kk < 64; kk += 32) {
        bf16x8 af0 = *(const bf16x8*)&As[wm * 32 + m16][kk + quad * 8];
        bf16x8 af1 = *(const bf16x8*)&As[wm * 32 + 16 + m16][kk + quad * 8];
        bf16x8 bfv[4];
        #pragma unroll
        for (int j = 0; j < 4; ++j)
          bfv[j] = *(const bf16x8*)&Bs[wn * 64 + j * 16 + m16][kk + quad * 8];
        #pragma unroll
        for (int j = 0; j < 4; ++j) {
          acc[0][j] = __builtin_amdgcn_mfma_f32_16x16x32_bf16(af0, bfv[j], acc[0][j], 0, 0, 0);
          acc[1][j] = __builtin_amdgcn_mfma_f32_16x16x32_bf16(af1, bfv[j], acc[1][j], 0, 0, 0);
        }
      }
    }

    // in-kernel norms (R2-verified reduction pattern)
    ssA += __shfl_xor(ssA, 1); ssA += __shfl_xor(ssA, 2);
    ssB += __shfl_xor(ssB, 1);
    if (sq == 0) Asn[sr] = ssA;
    if (bq == 0) Bsn[br] = ssB;
    __syncthreads();

    float na[2][4], nb[4];
    #pragma unroll
    for (int i = 0; i < 2; ++i)
      #pragma unroll
      for (int r = 0; r < 4; ++r)
        na[i][r] = Asn[wm * 32 + i * 16 + quad * 4 + r];
    #pragma unroll
    for (int j = 0; j < 4; ++j)
      nb[j] = Bsn[wn * 64 + j * 16 + m16];

    // rowNN partial: min over 4 col-frags then across 16 m16 lanes; plain store
    #pragma unroll
    for (int i = 0; i < 2; ++i) {
      #pragma unroll
      for (int r = 0; r < 4; ++r) {
        unsigned long long p = ~0ull;
        #pragma unroll
        for (int j = 0; j < 4; ++j) {
          float d = fmaxf(na[i][r] + nb[j] - 2.f * acc[i][j][r], 0.f);
          unsigned c = (unsigned)(col0 + wn * 64 + j * 16 + m16);
          unsigned long long pj = (((unsigned long long)__float_as_uint(d)) << 32) | c;
          p = pj < p ? pj : p;
        }
        #pragma unroll
        for (int s = 1; s < 16; s <<= 1) {
          unsigned long long q = __shfl_xor(p, s);
          p = q < p ? q : p;
        }
        if (m16 == 0)
          rowNNp[((size_t)b * LG + row0 + wm * 32 + i * 16 + quad * 4 + r) * 2 + by] = p;
      }
    }
    // colNN partial: min over 8 row-elems then across 4 quads; plain store
    #pragma unroll
    for (int j = 0; j < 4; ++j) {
      unsigned long long p = ~0ull;
      #pragma unroll
      for (int i = 0; i < 2; ++i) {
        #pragma unroll
        for (int r = 0; r < 4; ++r) {
          float d = fmaxf(na[i][r] + nb[j] - 2.f * acc[i][j][r], 0.f);
          unsigned rg = (unsigned)(row0 + wm * 32 + i * 16 + quad * 4 + r);
          unsigned long long pr = (((unsigned long long)__float_as_uint(d)) << 32) | rg;
          p = pr < p ? pr : p;
        }
      }
      unsigned long long q = __shfl_xor(p, 16); p = q < p ? q : p;
      q = __shfl_xor(p, 32); p = q < p ? q : p;
      if (quad == 0)
        colNNp[((size_t)b * LL + col0 + wn * 64 + j * 16 + m16) * 9 + bx] = p;
    }
    return;
  }

  if (blk < 1696) {
    // ---- raw Gram entries ----
    float (*sred)[5] = (float(*)[5])smem;
    int e = blk - 640;                         // 0..1055
    int zi = e >= 528; if (zi) e -= 528;
    const float* z = zi ? zb : za;
    float* Sz = S + zi * 1024;
    int p = 0, rem = e;
    while (rem >= 32 - p) { rem -= 32 - p; ++p; }
    int q = p + rem;
    const float4* zp = (const float4*)(z + (size_t)p * DZ);
    const float4* zq = (const float4*)(z + (size_t)q * DZ);
    float s = 0.f;
    #pragma unroll
    for (int ii = 0; ii < 8; ++ii) {
      int i = tid + ii * 256;
      float4 a = zp[i], bb = zq[i];
      s += a.x * bb.x + a.y * bb.y + a.z * bb.z + a.w * bb.w;
    }
    for (int off = 32; off; off >>= 1) s += __shfl_down(s, off);
    if (lane == 0) sred[wv][0] = s;
    __syncthreads();
    if (tid == 0) {
      float r = sred[0][0] + sred[1][0] + sred[2][0] + sred[3][0];
      Sz[p * 32 + q] = r;
      if (p != q) Sz[q * 32 + p] = r;
    }
    return;
  }

  // ---- per-feature stats ----
  {
    float (*sred)[5] = (float(*)[5])smem;
    int blkS = blk - 1696;
    if (blkS == 0 && tid == 0) cnt[0] = 0;     // reset tail done-counter
    int i = blkS * 256 + tid;
    float sa = 0.f, qa = 0.f, sb = 0.f, qb = 0.f, si = 0.f;
    #pragma unroll 8
    for (int b = 0; b < BATCH; ++b) {
      float va = za[(size_t)b * DZ + i];
      float vb = zb[(size_t)b * DZ + i];
      sa += va; qa += va * va;
      sb += vb; qb += vb * vb;
      float d = va - vb; si += d * d;
    }
    float ssa = qa - sa * sa * (1.f / 32.f);
    float ssb = qb - sb * sb * (1.f / 32.f);
    float v0 = si;
    float v1 = fmaxf(0.f, 1.f - sqrtf(ssa * (1.f / 31.f) + 1e-4f));
    float v2 = fmaxf(0.f, 1.f - sqrtf(ssb * (1.f / 31.f) + 1e-4f));
    float v3 = ssa * ssa, v4 = ssb * ssb;
    for (int off = 32; off; off >>= 1) {
      v0 += __shfl_down(v0, off); v1 += __shfl_down(v1, off);
      v2 += __shfl_down(v2, off); v3 += __shfl_down(v3, off);
      v4 += __shfl_down(v4, off);
    }
    if (lane == 0) {
      sred[wv][0] = v0; sred[wv][1] = v1; sred[wv][2] = v2;
      sred[wv][3] = v3; sred[wv][4] = v4;
    }
    __syncthreads();
    if (tid < 5)
      bsum[blkS * 5 + tid] =
          (double)(sred[0][tid] + sred[1][tid] + sred[2][tid] + sred[3][tid]);
  }
}

// ==================== launch B: sel V0/V1 (partials) + last-block final ====================
struct TailSmem {
  SelSmem sel;
  float t[2][32];
  double sacc[5];
  double smf[4];
  int isLast;
};

__global__ __launch_bounds__(256) void k_tail(
    const float* __restrict__ zgf, const float* __restrict__ zlf,
    const float* __restrict__ gg, const float* __restrict__ gl,
    const unsigned long long* __restrict__ rowNNp,
    const unsigned long long* __restrict__ colNNp,
    double* __restrict__ selsum, const double* __restrict__ bsum,
    const float* __restrict__ S, unsigned int* __restrict__ doneCnt,
    float* __restrict__ out) {
  __shared__ TailSmem ts;
  int tid = threadIdx.x;
  int b = blockIdx.x >> 1, V = blockIdx.x & 1;
  if (V == 0) sel_case<0>(ts.sel, b, zgf, zlf, gg, gl, rowNNp, colNNp, selsum);
  else        sel_case<1>(ts.sel, b, zgf, zlf, gg, gl, rowNNp, colNNp, selsum);

  if (tid == 0) {
    __threadfence();
    unsigned r = atomicAdd(doneCnt, 1u);
    ts.isLast = (r == 63) ? 1 : 0;
  }
  __syncthreads();
  if (!ts.isLast) return;
  __threadfence();

  if (tid < 32) {
    #pragma unroll
    for (int zi = 0; zi < 2; ++zi) {
      float tp = 0.f;
      for (int bb = 0; bb < 32; ++bb) tp += S[zi * 1024 + tid * 32 + bb];
      ts.t[zi][tid] = tp * (1.f / 32.f);
    }
  }
  if (tid < 5) {
    double s = 0.0;
    for (int blk2 = 0; blk2 < 32; ++blk2) s += bsum[blk2 * 5 + tid];
    ts.sacc[tid] = s;
  }
  if (tid >= 8 && tid < 12) {
    int v = tid - 8;
    double s = 0.0;
    for (int bb = 0; bb < 32; ++bb) s += selsum[v * 32 + bb];
    ts.smf[v] = s;
  }
  __syncthreads();
  if (tid < 64) {
    double total[2];
    #pragma unroll
    for (int zi = 0; zi < 2; ++zi) {
      float u = 0.f;
      for (int bb = 0; bb < 32; ++bb) u += ts.t[zi][bb];
      u *= (1.f / 32.f);
      double s = 0.0;
      for (int e2 = tid; e2 < 1024; e2 += 64) {
        int p = e2 >> 5, q = e2 & 31;
        float G = S[zi * 1024 + e2] - ts.t[zi][p] - ts.t[zi][q] + u;
        s += (double)G * (double)G;
      }
      for (int off = 32; off; off >>= 1) s += __shfl_down(s, off);
      total[zi] = s;
    }
    if (tid == 0) {
      double inv_g = ts.sacc[0] / (32.0 * 8192.0);
      double v = 0.5 * (ts.sacc[1] + ts.sacc[2]) / 8192.0;
      double c = (total[0] - ts.sacc[3] + total[1] - ts.sacc[4]) / (961.0 * 8192.0);
      double gloss = 25.0 * inv_g + 25.0 * v + c;
      double mfg = ts.smf[0] / (32.0 * 20.0 * 512.0);
      double mfl = ts.smf[1] / (32.0 * 4.0 * 512.0);
      double mgg = ts.smf[2] / (32.0 * 20.0 * 512.0);
      double mgl = ts.smf[3] / (32.0 * 4.0 * 512.0);
      double lloss = 25.0 * (0.5 * (mfg + mfl) + 0.5 * (mgg + mgl));
      out[0] = (float)(0.25 * gloss + 0.75 * lloss);
    }
  }
}

extern "C" void kernel_launch(void* const* d_in, const int* in_sizes, int n_in,
                              void* d_out, int out_size, void* d_ws, size_t ws_size,
                              hipStream_t stream) {
  const float* zg  = (const float*)d_in[0];
  const float* zl  = (const float*)d_in[1];
  const float* zgf = (const float*)d_in[2];
  const float* zlf = (const float*)d_in[3];
  const float* gg  = (const float*)d_in[4];
  const float* glo = (const float*)d_in[5];

  char* ws = (char*)d_ws;
  float* S       = (float*)(ws + OFF_S);
  double* bsum   = (double*)(ws + OFF_BSUM);
  double* selsum = (double*)(ws + OFF_SELSUM);
  unsigned int* cnt = (unsigned int*)(ws + OFF_CNT);
  unsigned long long* rowNNp = (unsigned long long*)(ws + OFF_RNP);
  unsigned long long* colNNp = (unsigned long long*)(ws + OFF_CNP);

  k_megaA<<<1728, 256, 0, stream>>>(zg, zl, zgf, zlf, gg, glo,
                                    bsum, S, rowNNp, colNNp, selsum, cnt);
  k_tail<<<64, 256, 0, stream>>>(zgf, zlf, gg, glo, rowNNp, colNNp,
                                 selsum, bsum, S, cnt, (float*)d_out);
}

// Round 7
// 137.422 us; speedup vs baseline: 1.6418x; 1.0077x over previous
//
#include <hip/hip_runtime.h>
#include <hip/hip_bf16.h>

#define BATCH 32
#define DZ    8192
#define LG    576
#define LL    256
#define CH    512

// ---- ws layout (byte offsets) ----
#define OFF_S      0                          // float[2*1024] raw Gram S
#define OFF_BSUM   8192                       // double[32*5]
#define OFF_SELSUM 9472                       // double[4*32]
#define OFF_CNT    10496                      // u32 selDone
#define OFF_RNP    10560                      // u64[BATCH*LG*2]  row-NN partials
#define OFF_CNP    305472                     // u64[BATCH*LL*9]  col-NN partials
#define WS_NEED    895296

typedef __attribute__((ext_vector_type(8))) short bf16x8;
typedef __attribute__((ext_vector_type(4))) float f32x4;

__device__ __forceinline__ unsigned short f2bf(float x) {
  union { __hip_bfloat16 h; unsigned short u; } cv;
  cv.h = __float2bfloat16(x);
  return cv.u;
}

__device__ __forceinline__ uint4 pack8(float4 lo, float4 hi) {
  union { unsigned short h[8]; uint4 u; } pk;
  pk.h[0] = f2bf(lo.x); pk.h[1] = f2bf(lo.y); pk.h[2] = f2bf(lo.z); pk.h[3] = f2bf(lo.w);
  pk.h[4] = f2bf(hi.x); pk.h[5] = f2bf(hi.y); pk.h[6] = f2bf(hi.z); pk.h[7] = f2bf(hi.w);
  return pk.u;
}

__device__ __forceinline__ float dot4(float4 v) {
  return v.x * v.x + v.y * v.y + v.z * v.z + v.w * v.w;
}

// -------- selection --------
struct SelSmem {
  unsigned long long keys[LG];
  unsigned int nnm[LG];
  float cxy[2 * LG];
  unsigned int plist[40];
  unsigned int cnt;
  float fred[4];
};

// V0/V1: feature NN from partials (x2 / x9).  V2/V3: grid NN.
template <int V>
__device__ __forceinline__ void sel_case(
    SelSmem& sm, int b,
    const float* __restrict__ zgf, const float* __restrict__ zlf,
    const float* __restrict__ gg, const float* __restrict__ gl,
    const unsigned long long* __restrict__ rowNNp,
    const unsigned long long* __restrict__ colNNp,
    double* __restrict__ selsum) {
  constexpr bool GDIR = (V == 0 || V == 2);
  constexpr int L1 = GDIR ? LG : LL;
  constexpr int L2 = GDIR ? LL : LG;
  constexpr int M  = GDIR ? 20 : 4;
  constexpr int NR = (L1 + 255) / 256;
  const float* fin  = GDIR ? zgf + (size_t)b * LG * CH : zlf + (size_t)b * LL * CH;
  const float* fcan = GDIR ? zlf + (size_t)b * LL * CH : zgf + (size_t)b * LG * CH;
  int tid = threadIdx.x, lane = tid & 63, wv = tid >> 6;
  if (tid == 0) sm.cnt = 0;

  if constexpr (V < 2) {
    constexpr int P = (V == 0) ? 2 : 9;
    const unsigned long long* src =
        (V == 0) ? rowNNp + (size_t)b * LG * 2 : colNNp + (size_t)b * LL * 9;
    #pragma unroll
    for (int s = 0; s < NR; ++s) {
      int l = tid + s * 256;
      if (l < L1) {
        const unsigned long long* q = src + (size_t)l * P;
        unsigned long long p = q[0];
        #pragma unroll
        for (int u = 1; u < P; ++u) { unsigned long long t2 = q[u]; p = t2 < p ? t2 : p; }
        sm.keys[l] = (p & 0xFFFFFFFF00000000ull) | (unsigned)l;
        sm.nnm[l] = (unsigned)(p & 0xFFFFFFFFu);
      }
    }
  } else {
    const float* gin  = (V == 2) ? gg + (size_t)b * LG * 2 : gl + (size_t)b * LL * 2;
    const float* gcan = (V == 2) ? gl + (size_t)b * LL * 2 : gg + (size_t)b * LG * 2;
    #pragma unroll
    for (int s = 0; s < (2 * L2 + 255) / 256; ++s) {
      int i = tid + s * 256;
      if (i < 2 * L2) sm.cxy[i] = gcan[i];
    }
    __syncthreads();
    float x[NR], y[NR], bd[NR];
    unsigned bi[NR];
    #pragma unroll
    for (int s = 0; s < NR; ++s) {
      int l = tid + s * 256;
      x[s] = (l < L1) ? gin[2 * l] : 0.f;
      y[s] = (l < L1) ? gin[2 * l + 1] : 0.f;
      bd[s] = 3.4e38f; bi[s] = 0;
    }
    const float2* c2 = (const float2*)sm.cxy;
    for (int m2 = 0; m2 < L2; m2 += 8) {
      float2 cc[8];
      #pragma unroll
      for (int u = 0; u < 8; ++u) cc[u] = c2[m2 + u];
      #pragma unroll
      for (int u = 0; u < 8; ++u)
        #pragma unroll
        for (int s = 0; s < NR; ++s) {
          float dx = x[s] - cc[u].x, dy = y[s] - cc[u].y;
          float d2 = dx * dx + dy * dy;
          if (d2 < bd[s]) { bd[s] = d2; bi[s] = (unsigned)(m2 + u); }  // first-min
        }
    }
    #pragma unroll
    for (int s = 0; s < NR; ++s) {
      int l = tid + s * 256;
      if (l < L1) {
        sm.keys[l] = ((unsigned long long)__float_as_uint(bd[s]) << 32) | (unsigned)l;
        sm.nnm[l] = bi[s];
      }
    }
  }
  __syncthreads();

  unsigned long long myk[NR];
  int rk[NR];
  #pragma unroll
  for (int s = 0; s < NR; ++s) {
    int l = tid + s * 256;
    myk[s] = (l < L1) ? sm.keys[l] : ~0ull;
    rk[s] = 0;
  }
  for (int j = 0; j < L1; j += 8) {
    unsigned long long kk[8];
    #pragma unroll
    for (int u = 0; u < 8; ++u) kk[u] = sm.keys[j + u];
    #pragma unroll
    for (int u = 0; u < 8; ++u)
      #pragma unroll
      for (int s = 0; s < NR; ++s) rk[s] += (kk[u] < myk[s]) ? 1 : 0;
  }
  #pragma unroll
  for (int s = 0; s < NR; ++s) {
    int l = tid + s * 256;
    if (l < L1 && rk[s] < M) {
      unsigned slot = atomicAdd(&sm.cnt, 1u);
      sm.plist[2 * slot] = (unsigned)l;
      sm.plist[2 * slot + 1] = sm.nnm[l];
    }
  }
  __syncthreads();

  float part = 0.f;
  #pragma unroll
  for (int rr = 0; rr < M / 4; ++rr) {
    int r = wv + rr * 4;
    const float4* a4 = (const float4*)(fin + (size_t)sm.plist[2 * r] * CH);
    const float4* c4 = (const float4*)(fcan + (size_t)sm.plist[2 * r + 1] * CH);
    float4 xa = a4[lane * 2], xb = a4[lane * 2 + 1];
    float4 ya = c4[lane * 2], yb = c4[lane * 2 + 1];
    float d0 = xa.x - ya.x, d1 = xa.y - ya.y, d2 = xa.z - ya.z, d3 = xa.w - ya.w;
    float d4 = xb.x - yb.x, d5 = xb.y - yb.y, d6 = xb.z - yb.z, d7 = xb.w - yb.w;
    part += d0 * d0 + d1 * d1 + d2 * d2 + d3 * d3 +
            d4 * d4 + d5 * d5 + d6 * d6 + d7 * d7;
  }
  for (int s = 32; s; s >>= 1) part += __shfl_down(part, s);
  if (lane == 0) sm.fred[wv] = part;
  __syncthreads();
  if (tid == 0)
    selsum[V * 32 + b] = (double)(sm.fred[0] + sm.fred[1] + sm.fred[2] + sm.fred[3]);
}

// ==================== launch A ====================
// blk [0,64)      : grid-space sel V2/V3 (longest serial blocks -> dispatched first)
// blk [64,640)    : feat MFMA, fp32-direct, double-buffered LDS (1 barrier/step)
// blk [640,1696)  : raw Gram entries
// blk [1696,1728) : per-feature stats  (blk 1696 resets tail done-counter)
__global__ __launch_bounds__(256) void k_megaA(
    const float* __restrict__ za, const float* __restrict__ zb,
    const float* __restrict__ zgf, const float* __restrict__ zlf,
    const float* __restrict__ gg, const float* __restrict__ gl,
    double* __restrict__ bsum, float* __restrict__ S,
    unsigned long long* __restrict__ rowNNp, unsigned long long* __restrict__ colNNp,
    double* __restrict__ selsum, unsigned int* __restrict__ cnt) {
  __shared__ __align__(16) char smem[31488];
  int tid = threadIdx.x, lane = tid & 63, wv = tid >> 6;
  int blk = blockIdx.x;

  if (blk < 64) {
    SelSmem& sm = *reinterpret_cast<SelSmem*>(smem);
    int b2 = blk >> 1;
    if (blk & 1) sel_case<3>(sm, b2, zgf, zlf, gg, gl, rowNNp, colNNp, selsum);
    else         sel_case<2>(sm, b2, zgf, zlf, gg, gl, rowNNp, colNNp, selsum);
    return;
  }

  if (blk < 640) {
    // ---- feat: 64x128 tile, BK=32, double-buffered LDS (pitch 40 shorts) ----
    int fblk = blk - 64;
    int fs = (fblk & 7) * 72 + (fblk >> 3);   // XCD swizzle (576 % 8 == 0)
    int b = fs / 18, rr_ = fs % 18;
    int by = rr_ / 9, bx = rr_ % 9;
    int row0 = bx * 64, col0 = by * 128;

    unsigned short (*As0)[40] = (unsigned short(*)[40])smem;              // 5120
    unsigned short (*Bs0)[40] = (unsigned short(*)[40])(smem + 5120);     // 10240
    unsigned short (*As1)[40] = (unsigned short(*)[40])(smem + 15360);    // 5120
    unsigned short (*Bs1)[40] = (unsigned short(*)[40])(smem + 20480);    // 10240
    float* Asn = (float*)(smem + 30720);                                  // 256
    float* Bsn = (float*)(smem + 30976);                                  // 512

    const int m16 = lane & 15, quad = lane >> 4;
    const int wm = wv >> 1, wn = wv & 1;
    const float* Ag = zgf + ((size_t)(b * LG + row0)) * CH;
    const float* Bg = zlf + ((size_t)(b * LL + col0)) * CH;
    const int sr = tid >> 2, sq = tid & 3;   // A: 64 rows x 8-float chunks
    const int br = tid >> 1, bq = tid & 1;   // B: 128 rows x 16-float chunks

    f32x4 acc[2][4] = {};
    float ssA = 0.f, ssB = 0.f;
    float4 a0, a1, b0, b1, b2, b3;

    const float* apb = Ag + (size_t)sr * CH + sq * 8;
    const float* bpb = Bg + (size_t)br * CH + bq * 16;

    // prologue: load s=0, pack -> buf0, load s=1
    a0 = *(const float4*)(apb);     a1 = *(const float4*)(apb + 4);
    b0 = *(const float4*)(bpb);     b1 = *(const float4*)(bpb + 4);
    b2 = *(const float4*)(bpb + 8); b3 = *(const float4*)(bpb + 12);
    *(uint4*)&As0[sr][sq * 8]       = pack8(a0, a1);
    *(uint4*)&Bs0[br][bq * 16]      = pack8(b0, b1);
    *(uint4*)&Bs0[br][bq * 16 + 8]  = pack8(b2, b3);
    ssA += dot4(a0) + dot4(a1);
    ssB += dot4(b0) + dot4(b1) + dot4(b2) + dot4(b3);
    a0 = *(const float4*)(apb + 32);      a1 = *(const float4*)(apb + 36);
    b0 = *(const float4*)(bpb + 32);      b1 = *(const float4*)(bpb + 36);
    b2 = *(const float4*)(bpb + 40);      b3 = *(const float4*)(bpb + 44);
    __syncthreads();

    #pragma unroll
    for (int k = 0; k < 8; ++k) {
      // ---- t = 2k : compute buf0 ; pack regs(2k+1)->buf1 ; load (2k+2) ----
      {
        bf16x8 af0 = *(const bf16x8*)&As0[wm * 32 + m16][quad * 8];
        bf16x8 af1 = *(const bf16x8*)&As0[wm * 32 + 16 + m16][quad * 8];
        bf16x8 bfv[4];
        #pragma unroll
        for (int j = 0; j < 4; ++j)
          bfv[j] = *(const bf16x8*)&Bs0[wn * 64 + j * 16 + m16][quad * 8];
        #pragma unroll
        for (int j = 0; j < 4; ++j) {
          acc[0][j] = __builtin_amdgcn_mfma_f32_16x16x32_bf16(af0, bfv[j], acc[0][j], 0, 0, 0);
          acc[1][j] = __builtin_amdgcn_mfma_f32_16x16x32_bf16(af1, bfv[j], acc[1][j], 0, 0, 0);
        }
        *(uint4*)&As1[sr][sq * 8]      = pack8(a0, a1);
        *(uint4*)&Bs1[br][bq * 16]     = pack8(b0, b1);
        *(uint4*)&Bs1[br][bq * 16 + 8] = pack8(b2, b3);
        ssA += dot4(a0) + dot4(a1);
        ssB += dot4(b0) + dot4(b1) + dot4(b2) + dot4(b3);
        if (k < 7) {
          int k0 = (2 * k + 2) * 32;
          a0 = *(const float4*)(apb + k0);      a1 = *(const float4*)(apb + k0 + 4);
          b0 = *(const float4*)(bpb + k0);      b1 = *(const float4*)(bpb + k0 + 4);
          b2 = *(const float4*)(bpb + k0 + 8);  b3 = *(const float4*)(bpb + k0 + 12);
        }
        __syncthreads();
      }
      // ---- t = 2k+1 : compute buf1 ; pack regs(2k+2)->buf0 ; load (2k+3) ----
      {
        bf16x8 af0 = *(const bf16x8*)&As1[wm * 32 + m16][quad * 8];
        bf16x8 af1 = *(const bf16x8*)&As1[wm * 32 + 16 + m16][quad * 8];
        bf16x8 bfv[4];
        #pragma unroll
        for (int j = 0; j < 4; ++j)
          bfv[j] = *(const bf16x8*)&Bs1[wn * 64 + j * 16 + m16][quad * 8];
        #pragma unroll
        for (int j = 0; j < 4; ++j) {
          acc[0][j] = __builtin_amdgcn_mfma_f32_16x16x32_bf16(af0, bfv[j], acc[0][j], 0, 0, 0);
          acc[1][j] = __builtin_amdgcn_mfma_f32_16x16x32_bf16(af1, bfv[j], acc[1][j], 0, 0, 0);
        }
        if (k < 7) {
          *(uint4*)&As0[sr][sq * 8]      = pack8(a0, a1);
          *(uint4*)&Bs0[br][bq * 16]     = pack8(b0, b1);
          *(uint4*)&Bs0[br][bq * 16 + 8] = pack8(b2, b3);
          ssA += dot4(a0) + dot4(a1);
          ssB += dot4(b0) + dot4(b1) + dot4(b2) + dot4(b3);
          int k0 = (2 * k + 3) * 32;
          a0 = *(const float4*)(apb + k0);      a1 = *(const float4*)(apb + k0 + 4);
          b0 = *(const float4*)(bpb + k0);      b1 = *(const float4*)(bpb + k0 + 4);
          b2 = *(const float4*)(bpb + k0 + 8);  b3 = *(const float4*)(bpb + k0 + 12);
          __syncthreads();
        }
      }
    }

    // in-kernel norms: reduce over chunk owners (A: sq lanes 4s..4s+3; B: bq pairs)
    ssA += __shfl_xor(ssA, 1); ssA += __shfl_xor(ssA, 2);
    ssB += __shfl_xor(ssB, 1);
    __syncthreads();
    if (sq == 0) Asn[sr] = ssA;
    if (bq == 0) Bsn[br] = ssB;
    __syncthreads();

    float na[2][4], nb[4];
    #pragma unroll
    for (int i = 0; i < 2; ++i)
      #pragma unroll
      for (int r = 0; r < 4; ++r)
        na[i][r] = Asn[wm * 32 + i * 16 + quad * 4 + r];
    #pragma unroll
    for (int j = 0; j < 4; ++j)
      nb[j] = Bsn[wn * 64 + j * 16 + m16];

    // rowNN partial: min over 4 col-frags then across 16 m16 lanes; plain store
    #pragma unroll
    for (int i = 0; i < 2; ++i) {
      #pragma unroll
      for (int r = 0; r < 4; ++r) {
        unsigned long long p = ~0ull;
        #pragma unroll
        for (int j = 0; j < 4; ++j) {
          float d = fmaxf(na[i][r] + nb[j] - 2.f * acc[i][j][r], 0.f);
          unsigned c = (unsigned)(col0 + wn * 64 + j * 16 + m16);
          unsigned long long pj = (((unsigned long long)__float_as_uint(d)) << 32) | c;
          p = pj < p ? pj : p;
        }
        #pragma unroll
        for (int s = 1; s < 16; s <<= 1) {
          unsigned long long q = __shfl_xor(p, s);
          p = q < p ? q : p;
        }
        if (m16 == 0)
          rowNNp[((size_t)b * LG + row0 + wm * 32 + i * 16 + quad * 4 + r) * 2 + by] = p;
      }
    }
    // colNN partial: min over 8 row-elems then across 4 quads; plain store
    #pragma unroll
    for (int j = 0; j < 4; ++j) {
      unsigned long long p = ~0ull;
      #pragma unroll
      for (int i = 0; i < 2; ++i) {
        #pragma unroll
        for (int r = 0; r < 4; ++r) {
          float d = fmaxf(na[i][r] + nb[j] - 2.f * acc[i][j][r], 0.f);
          unsigned rg = (unsigned)(row0 + wm * 32 + i * 16 + quad * 4 + r);
          unsigned long long pr = (((unsigned long long)__float_as_uint(d)) << 32) | rg;
          p = pr < p ? pr : p;
        }
      }
      unsigned long long q = __shfl_xor(p, 16); p = q < p ? q : p;
      q = __shfl_xor(p, 32); p = q < p ? q : p;
      if (quad == 0)
        colNNp[((size_t)b * LL + col0 + wn * 64 + j * 16 + m16) * 9 + bx] = p;
    }
    return;
  }

  if (blk < 1696) {
    // ---- raw Gram entries ----
    float (*sred)[5] = (float(*)[5])smem;
    int e = blk - 640;                         // 0..1055
    int zi = e >= 528; if (zi) e -= 528;
    const float* z = zi ? zb : za;
    float* Sz = S + zi * 1024;
    int p = 0, rem = e;
    while (rem >= 32 - p) { rem -= 32 - p; ++p; }
    int q = p + rem;
    const float4* zp = (const float4*)(z + (size_t)p * DZ);
    const float4* zq = (const float4*)(z + (size_t)q * DZ);
    float s = 0.f;
    #pragma unroll
    for (int ii = 0; ii < 8; ++ii) {
      int i = tid + ii * 256;
      float4 a = zp[i], bb = zq[i];
      s += a.x * bb.x + a.y * bb.y + a.z * bb.z + a.w * bb.w;
    }
    for (int off = 32; off; off >>= 1) s += __shfl_down(s, off);
    if (lane == 0) sred[wv][0] = s;
    __syncthreads();
    if (tid == 0) {
      float r = sred[0][0] + sred[1][0] + sred[2][0] + sred[3][0];
      Sz[p * 32 + q] = r;
      if (p != q) Sz[q * 32 + p] = r;
    }
    return;
  }

  // ---- per-feature stats ----
  {
    float (*sred)[5] = (float(*)[5])smem;
    int blkS = blk - 1696;
    if (blkS == 0 && tid == 0) cnt[0] = 0;     // reset tail done-counter
    int i = blkS * 256 + tid;
    float sa = 0.f, qa = 0.f, sb = 0.f, qb = 0.f, si = 0.f;
    #pragma unroll 8
    for (int b = 0; b < BATCH; ++b) {
      float va = za[(size_t)b * DZ + i];
      float vb = zb[(size_t)b * DZ + i];
      sa += va; qa += va * va;
      sb += vb; qb += vb * vb;
      float d = va - vb; si += d * d;
    }
    float ssa = qa - sa * sa * (1.f / 32.f);
    float ssb = qb - sb * sb * (1.f / 32.f);
    float v0 = si;
    float v1 = fmaxf(0.f, 1.f - sqrtf(ssa * (1.f / 31.f) + 1e-4f));
    float v2 = fmaxf(0.f, 1.f - sqrtf(ssb * (1.f / 31.f) + 1e-4f));
    float v3 = ssa * ssa, v4 = ssb * ssb;
    for (int off = 32; off; off >>= 1) {
      v0 += __shfl_down(v0, off); v1 += __shfl_down(v1, off);
      v2 += __shfl_down(v2, off); v3 += __shfl_down(v3, off);
      v4 += __shfl_down(v4, off);
    }
    if (lane == 0) {
      sred[wv][0] = v0; sred[wv][1] = v1; sred[wv][2] = v2;
      sred[wv][3] = v3; sred[wv][4] = v4;
    }
    __syncthreads();
    if (tid < 5)
      bsum[blkS * 5 + tid] =
          (double)(sred[0][tid] + sred[1][tid] + sred[2][tid] + sred[3][tid]);
  }
}

// ==================== launch B: sel V0/V1 (partials) + last-block final ====================
struct TailSmem {
  SelSmem sel;
  float t[2][32];
  double sacc[5];
  double smf[4];
  int isLast;
};

__global__ __launch_bounds__(256) void k_tail(
    const float* __restrict__ zgf, const float* __restrict__ zlf,
    const float* __restrict__ gg, const float* __restrict__ gl,
    const unsigned long long* __restrict__ rowNNp,
    const unsigned long long* __restrict__ colNNp,
    double* __restrict__ selsum, const double* __restrict__ bsum,
    const float* __restrict__ S, unsigned int* __restrict__ doneCnt,
    float* __restrict__ out) {
  __shared__ TailSmem ts;
  int tid = threadIdx.x;
  int b = blockIdx.x >> 1, V = blockIdx.x & 1;
  if (V == 0) sel_case<0>(ts.sel, b, zgf, zlf, gg, gl, rowNNp, colNNp, selsum);
  else        sel_case<1>(ts.sel, b, zgf, zlf, gg, gl, rowNNp, colNNp, selsum);

  if (tid == 0) {
    __threadfence();
    unsigned r = atomicAdd(doneCnt, 1u);
    ts.isLast = (r == 63) ? 1 : 0;
  }
  __syncthreads();
  if (!ts.isLast) return;
  __threadfence();

  if (tid < 32) {
    #pragma unroll
    for (int zi = 0; zi < 2; ++zi) {
      float tp = 0.f;
      for (int bb = 0; bb < 32; ++bb) tp += S[zi * 1024 + tid * 32 + bb];
      ts.t[zi][tid] = tp * (1.f / 32.f);
    }
  }
  if (tid < 5) {
    double s = 0.0;
    for (int blk2 = 0; blk2 < 32; ++blk2) s += bsum[blk2 * 5 + tid];
    ts.sacc[tid] = s;
  }
  if (tid >= 8 && tid < 12) {
    int v = tid - 8;
    double s = 0.0;
    for (int bb = 0; bb < 32; ++bb) s += selsum[v * 32 + bb];
    ts.smf[v] = s;
  }
  __syncthreads();
  if (tid < 64) {
    double total[2];
    #pragma unroll
    for (int zi = 0; zi < 2; ++zi) {
      float u = 0.f;
      for (int bb = 0; bb < 32; ++bb) u += ts.t[zi][bb];
      u *= (1.f / 32.f);
      double s = 0.0;
      for (int e2 = tid; e2 < 1024; e2 += 64) {
        int p = e2 >> 5, q = e2 & 31;
        float G = S[zi * 1024 + e2] - ts.t[zi][p] - ts.t[zi][q] + u;
        s += (double)G * (double)G;
      }
      for (int off = 32; off; off >>= 1) s += __shfl_down(s, off);
      total[zi] = s;
    }
    if (tid == 0) {
      double inv_g = ts.sacc[0] / (32.0 * 8192.0);
      double v = 0.5 * (ts.sacc[1] + ts.sacc[2]) / 8192.0;
      double c = (total[0] - ts.sacc[3] + total[1] - ts.sacc[4]) / (961.0 * 8192.0);
      double gloss = 25.0 * inv_g + 25.0 * v + c;
      double mfg = ts.smf[0] / (32.0 * 20.0 * 512.0);
      double mfl = ts.smf[1] / (32.0 * 4.0 * 512.0);
      double mgg = ts.smf[2] / (32.0 * 20.0 * 512.0);
      double mgl = ts.smf[3] / (32.0 * 4.0 * 512.0);
      double lloss = 25.0 * (0.5 * (mfg + mfl) + 0.5 * (mgg + mgl));
      out[0] = (float)(0.25 * gloss + 0.75 * lloss);
    }
  }
}

extern "C" void kernel_launch(void* const* d_in, const int* in_sizes, int n_in,
                              void* d_out, int out_size, void* d_ws, size_t ws_size,
                              hipStream_t stream) {
  const float* zg  = (const float*)d_in[0];
  const float* zl  = (const float*)d_in[1];
  const float* zgf = (const float*)d_in[2];
  const float* zlf = (const float*)d_in[3];
  const float* gg  = (const float*)d_in[4];
  const float* glo = (const float*)d_in[5];

  char* ws = (char*)d_ws;
  float* S       = (float*)(ws + OFF_S);
  double* bsum   = (double*)(ws + OFF_BSUM);
  double* selsum = (double*)(ws + OFF_SELSUM);
  unsigned int* cnt = (unsigned int*)(ws + OFF_CNT);
  unsigned long long* rowNNp = (unsigned long long*)(ws + OFF_RNP);
  unsigned long long* colNNp = (unsigned long long*)(ws + OFF_CNP);

  k_megaA<<<1728, 256, 0, stream>>>(zg, zl, zgf, zlf, gg, glo,
                                    bsum, S, rowNNp, colNNp, selsum, cnt);
  k_tail<<<64, 256, 0, stream>>>(zgf, zlf, gg, glo, rowNNp, colNNp,
                                 selsum, bsum, S, cnt, (float*)d_out);
}